// Round 1
// baseline (761.284 us; speedup 1.0000x reference)
//
#include <hip/hip_runtime.h>
#include <hip/hip_bf16.h>

// GPT3 attention block: y = Dense(MHA(split(XQ Wq^T+bq), ...causal...)) 
// B=2, S=2048, D=2048, H=16, Dh=128.
// Strategy: convert to bf16, 4x MFMA GEMMs + flash attention, fp32 accum.
// Workspace layout (needs ~92 MB):
//   Xbf  [4096*2048] bf16  (reused for q,k,v activations)
//   Wbf  [2048*2048] bf16  (reused for wq,wk,wv,dense)
//   Qh,Kh,Vh,Obf [4096*2048] bf16 each

typedef __bf16 bf16x8 __attribute__((ext_vector_type(8)));
typedef float f32x4 __attribute__((ext_vector_type(4)));
typedef unsigned short u16;

#define DEV static __device__ __forceinline__

DEV void gload_lds16(const void* g, void* l) {
  __builtin_amdgcn_global_load_lds(
      (const __attribute__((address_space(1))) void*)g,
      (__attribute__((address_space(3))) void*)l, 16, 0, 0);
}

DEV f32x4 mfma16(bf16x8 a, bf16x8 b, f32x4 c) {
  return __builtin_amdgcn_mfma_f32_16x16x32_bf16(a, b, c, 0, 0, 0);
}

DEV u16 f2bf(float x) {
  return __builtin_bit_cast(u16, __float2bfloat16(x));
}

// ---------------- fp32 -> bf16 conversion (vectorized) ----------------
__global__ void __launch_bounds__(256) conv_f32_bf16(
    const float* __restrict__ in, u16* __restrict__ out) {
  const size_t i = ((size_t)blockIdx.x * 256 + threadIdx.x) * 4;
  const float4 v = *reinterpret_cast<const float4*>(in + i);
  ushort4 o;
  o.x = f2bf(v.x); o.y = f2bf(v.y); o.z = f2bf(v.z); o.w = f2bf(v.w);
  *reinterpret_cast<ushort4*>(out + i) = o;
}

// ---------------- GEMM: C[M][N] = A[M][K] @ B[N][K]^T + bias ----------
// 128x128 tile, BK=32, 4 waves (2x2), each wave 64x64 via 4x4 16x16x32 MFMA.
#define BM 128
#define BN 128
#define BK 32

__global__ void __launch_bounds__(256) gemm_bt(
    const u16* __restrict__ A,   // [M][K] bf16
    const u16* __restrict__ Bw,  // [N][K] bf16
    const float* __restrict__ bias,  // [N]
    void* __restrict__ Cout, const int M, const int N, const int K,
    const int out_f32) {
  __shared__ u16 As[BM * BK];  // 8 KB
  __shared__ u16 Bs[BN * BK];  // 8 KB

  const int tid = threadIdx.x;
  const int lane = tid & 63;
  const int w = tid >> 6;
  const int wr = w >> 1, wc = w & 1;
  const int g = lane >> 4;
  const int r16 = lane & 15;
  const int m0 = blockIdx.x * BM, n0 = blockIdx.y * BN;

  const f32x4 zero = {0.f, 0.f, 0.f, 0.f};
  f32x4 acc[4][4];
#pragma unroll
  for (int i = 0; i < 4; ++i)
#pragma unroll
    for (int j = 0; j < 4; ++j) acc[i][j] = zero;

  // staging: per round, each wave DMAs 16 rows x 64B into LDS (lane*16B dest)
  const int srow = w * 16 + (lane >> 2);
  const int scol = (lane & 3) * 8;
  const u16* ga0 = A + (size_t)(m0 + srow) * K + scol;
  const u16* ga1 = A + (size_t)(m0 + 64 + srow) * K + scol;
  const u16* gb0 = Bw + (size_t)(n0 + srow) * K + scol;
  const u16* gb1 = Bw + (size_t)(n0 + 64 + srow) * K + scol;
  u16* la0 = &As[(w * 16) * BK];
  u16* la1 = &As[(64 + w * 16) * BK];
  u16* lb0 = &Bs[(w * 16) * BK];
  u16* lb1 = &Bs[(64 + w * 16) * BK];

  for (int kt = 0; kt < K; kt += BK) {
    gload_lds16(ga0 + kt, la0);
    gload_lds16(ga1 + kt, la1);
    gload_lds16(gb0 + kt, lb0);
    gload_lds16(gb1 + kt, lb1);
    __syncthreads();  // compiler drains vmcnt before barrier

    bf16x8 af[4], bf[4];
#pragma unroll
    for (int i = 0; i < 4; ++i) {
      af[i] = *reinterpret_cast<const bf16x8*>(
          &As[(wr * 64 + i * 16 + r16) * BK + g * 8]);
      bf[i] = *reinterpret_cast<const bf16x8*>(
          &Bs[(wc * 64 + i * 16 + r16) * BK + g * 8]);
    }
#pragma unroll
    for (int i = 0; i < 4; ++i)
#pragma unroll
      for (int j = 0; j < 4; ++j)
        acc[i][j] = mfma16(af[i], bf[j], acc[i][j]);
    __syncthreads();
  }

  // epilogue: C/D layout col=lane&15, row=(lane>>4)*4+reg
  const int cbase = n0 + wc * 64 + r16;
  const int rbase = m0 + wr * 64 + g * 4;
#pragma unroll
  for (int i = 0; i < 4; ++i) {
#pragma unroll
    for (int j = 0; j < 4; ++j) {
      const int c = cbase + j * 16;
      const float bv = bias[c];
#pragma unroll
      for (int r = 0; r < 4; ++r) {
        const float v = acc[i][j][r] + bv;
        const size_t idx = (size_t)(rbase + i * 16 + r) * N + c;
        if (out_f32) {
          ((float*)Cout)[idx] = v;
        } else {
          ((u16*)Cout)[idx] = f2bf(v);
        }
      }
    }
  }
}

// ---------------- causal flash attention ------------------------------
// block = 4 waves; each wave owns 16 Q rows; block owns 64 rows of one (b,h).
// K tile 32x128 staged row-major (global_load_lds); V tile transposed in LDS.
#define SEQ 2048
#define DMODEL 2048
#define DH 128
#define QBLK 64
#define KBLK 32
#define VT_STRIDE 48  // pad: 96B rows, 16B aligned, spreads banks on b128 reads
#define PL_STRIDE 40  // pad: 80B rows, 16B aligned
#define SCALE 0.08838834764831843f

__global__ void __launch_bounds__(256) flash_attn(
    const u16* __restrict__ Qh, const u16* __restrict__ Kh,
    const u16* __restrict__ Vh, u16* __restrict__ O) {
  __shared__ u16 Ks[KBLK * DH];          // 8 KB row-major [k][d]
  __shared__ u16 Vt[DH * VT_STRIDE];     // 12 KB transposed [d][k]
  __shared__ u16 Pl[4][16 * PL_STRIDE];  // 5 KB per-wave P tiles

  const int tid = threadIdx.x;
  const int lane = tid & 63;
  const int w = tid >> 6;
  const int g = lane >> 4;   // 0..3
  const int r16 = lane & 15; // 0..15

  const int qt = blockIdx.x & 31;
  const int h = (blockIdx.x >> 5) & 15;
  const int b = blockIdx.x >> 9;
  const int q0 = qt * QBLK;
  const size_t rowbase = (size_t)b * SEQ;
  const int hoff = h * DH;

  // Q fragments in registers: wave's 16 rows x 128 (4 chunks of K=32)
  bf16x8 aq[4];
  const size_t qrow = rowbase + q0 + w * 16 + r16;
#pragma unroll
  for (int c = 0; c < 4; ++c)
    aq[c] = *reinterpret_cast<const bf16x8*>(
        &Qh[qrow * DMODEL + hoff + c * 32 + g * 8]);

  const f32x4 zero = {0.f, 0.f, 0.f, 0.f};
  f32x4 oacc[8];
#pragma unroll
  for (int df = 0; df < 8; ++df) oacc[df] = zero;
  float mrow[4] = {-1e30f, -1e30f, -1e30f, -1e30f};
  float lrow[4] = {0.f, 0.f, 0.f, 0.f};

  // V staging indices: thread -> (row, col8)
  const int sr = tid >> 4;        // 0..15
  const int sc = (tid & 15) * 8;  // 0..120

  const int nkt = q0 / KBLK + 2;  // causal: only tiles with k0 <= q0+63

  for (int kt = 0; kt < nkt; ++kt) {
    const int k0 = kt * KBLK;
    __syncthreads();  // prev tile fully consumed
    // stage K tile: 2 DMA rounds per wave (16B/lane, linear LDS)
#pragma unroll
    for (int rr = 0; rr < 2; ++rr) {
      const int krow = rr * 16 + w * 4 + g;
      gload_lds16(&Kh[(rowbase + k0 + krow) * DMODEL + hoff + r16 * 8],
                  &Ks[(rr * 16 + w * 4) * DH]);
    }
    // stage V transposed (reg round-trip)
#pragma unroll
    for (int rr = 0; rr < 2; ++rr) {
      const int vrow = rr * 16 + sr;
      const uint4 vv = *reinterpret_cast<const uint4*>(
          &Vh[(rowbase + k0 + vrow) * DMODEL + hoff + sc]);
      const u16* pv = reinterpret_cast<const u16*>(&vv);
#pragma unroll
      for (int j = 0; j < 8; ++j)
        Vt[(sc + j) * VT_STRIDE + vrow] = pv[j];
    }
    __syncthreads();

    // S = Q K^T  (two 16-col k-fragments)
    f32x4 s0 = zero, s1 = zero;
#pragma unroll
    for (int c = 0; c < 4; ++c) {
      const bf16x8 bk0 = *reinterpret_cast<const bf16x8*>(
          &Ks[r16 * DH + c * 32 + g * 8]);
      const bf16x8 bk1 = *reinterpret_cast<const bf16x8*>(
          &Ks[(16 + r16) * DH + c * 32 + g * 8]);
      s0 = mfma16(aq[c], bk0, s0);
      s1 = mfma16(aq[c], bk1, s1);
    }

    // online softmax (rows = g*4+j, cols = r16 / 16+r16)
    float p0[4], p1[4];
    const int qg = q0 + w * 16 + g * 4;
#pragma unroll
    for (int j = 0; j < 4; ++j) {
      const int qr = qg + j;
      float a = (k0 + r16) <= qr ? s0[j] * SCALE : -1e9f;
      float bb = (k0 + 16 + r16) <= qr ? s1[j] * SCALE : -1e9f;
      float mx = fmaxf(a, bb);
      mx = fmaxf(mx, __shfl_xor(mx, 1));
      mx = fmaxf(mx, __shfl_xor(mx, 2));
      mx = fmaxf(mx, __shfl_xor(mx, 4));
      mx = fmaxf(mx, __shfl_xor(mx, 8));
      const float mnew = fmaxf(mrow[j], mx);
      const float alpha = __expf(mrow[j] - mnew);
      mrow[j] = mnew;
      const float e0 = __expf(a - mnew);
      const float e1 = __expf(bb - mnew);
      p0[j] = e0; p1[j] = e1;
      float rs = e0 + e1;
      rs += __shfl_xor(rs, 1);
      rs += __shfl_xor(rs, 2);
      rs += __shfl_xor(rs, 4);
      rs += __shfl_xor(rs, 8);
      lrow[j] = lrow[j] * alpha + rs;
#pragma unroll
      for (int df = 0; df < 8; ++df) oacc[df][j] *= alpha;
    }

    // P (C-layout) -> LDS -> A-fragment layout
#pragma unroll
    for (int j = 0; j < 4; ++j) {
      Pl[w][(g * 4 + j) * PL_STRIDE + r16] = f2bf(p0[j]);
      Pl[w][(g * 4 + j) * PL_STRIDE + 16 + r16] = f2bf(p1[j]);
    }
    const bf16x8 pf = *reinterpret_cast<const bf16x8*>(
        &Pl[w][r16 * PL_STRIDE + g * 8]);

    // O += P V
#pragma unroll
    for (int df = 0; df < 8; ++df) {
      const bf16x8 bv = *reinterpret_cast<const bf16x8*>(
          &Vt[(df * 16 + r16) * VT_STRIDE + g * 8]);
      oacc[df] = mfma16(pf, bv, oacc[df]);
    }
  }

  // epilogue: O[b*S+q][h*128+d] = acc / l
#pragma unroll
  for (int df = 0; df < 8; ++df) {
#pragma unroll
    for (int j = 0; j < 4; ++j) {
      const size_t q = rowbase + q0 + w * 16 + g * 4 + j;
      O[q * DMODEL + hoff + df * 16 + r16] =
          f2bf(oacc[df][j] / lrow[j]);
    }
  }
}

// ---------------- launcher --------------------------------------------
extern "C" void kernel_launch(void* const* d_in, const int* in_sizes, int n_in,
                              void* d_out, int out_size, void* d_ws,
                              size_t ws_size, hipStream_t stream) {
  const int Bv = 2, S = 2048, D = 2048;
  const int M = Bv * S;             // 4096
  const size_t NT = (size_t)M * D;  // 8388608 activation elems
  const size_t NW = (size_t)D * D;  // 4194304 weight elems

  const float* q = (const float*)d_in[0];
  const float* k = (const float*)d_in[1];
  const float* v = (const float*)d_in[2];
  // d_in[3] = mask (deterministic causal triu) — folded into the kernel
  const float* wq_w = (const float*)d_in[4];
  const float* wq_b = (const float*)d_in[5];
  const float* wk_w = (const float*)d_in[6];
  const float* wk_b = (const float*)d_in[7];
  const float* wv_w = (const float*)d_in[8];
  const float* wv_b = (const float*)d_in[9];
  const float* dw = (const float*)d_in[10];
  const float* db = (const float*)d_in[11];
  float* out = (float*)d_out;

  char* ws = (char*)d_ws;
  u16* Xbf = (u16*)ws;                      // 16 MB
  u16* Wbf = (u16*)(ws + NT * 2);           // 8 MB
  u16* Qh = (u16*)(ws + NT * 2 + NW * 2);   // 16 MB
  u16* Kh = Qh + NT;
  u16* Vh = Kh + NT;
  u16* Obf = Vh + NT;
  // total ws use: 2*NT + 2*NW + 8*NT = ~92 MB

  const dim3 blk(256);
  const dim3 gact((unsigned)(NT / 1024));
  const dim3 gw((unsigned)(NW / 1024));
  const dim3 ggemm(M / BM, D / BN);
  const dim3 gattn(Bv * 16 * (S / QBLK));  // 1024

  // Q projection
  conv_f32_bf16<<<gact, blk, 0, stream>>>(q, Xbf);
  conv_f32_bf16<<<gw, blk, 0, stream>>>(wq_w, Wbf);
  gemm_bt<<<ggemm, blk, 0, stream>>>(Xbf, Wbf, wq_b, Qh, M, D, D, 0);
  // K projection
  conv_f32_bf16<<<gact, blk, 0, stream>>>(k, Xbf);
  conv_f32_bf16<<<gw, blk, 0, stream>>>(wk_w, Wbf);
  gemm_bt<<<ggemm, blk, 0, stream>>>(Xbf, Wbf, wk_b, Kh, M, D, D, 0);
  // V projection
  conv_f32_bf16<<<gact, blk, 0, stream>>>(v, Xbf);
  conv_f32_bf16<<<gw, blk, 0, stream>>>(wv_w, Wbf);
  gemm_bt<<<ggemm, blk, 0, stream>>>(Xbf, Wbf, wv_b, Vh, M, D, D, 0);
  // attention
  flash_attn<<<gattn, blk, 0, stream>>>(Qh, Kh, Vh, Obf);
  // output projection (fp32 out)
  conv_f32_bf16<<<gw, blk, 0, stream>>>(dw, Wbf);
  gemm_bt<<<ggemm, blk, 0, stream>>>(Obf, Wbf, db, out, M, D, D, 1);
}

// Round 2
// 548.894 us; speedup vs baseline: 1.3869x; 1.3869x over previous
//
#include <hip/hip_runtime.h>
#include <hip/hip_bf16.h>

// GPT3 attention block, B=2 S=2048 D=2048 H=16 Dh=128.
// bf16 MFMA GEMMs + flash attention with swizzled LDS.

typedef __bf16 bf16x8 __attribute__((ext_vector_type(8)));
typedef float f32x4 __attribute__((ext_vector_type(4)));
typedef unsigned short u16;

#define DEV static __device__ __forceinline__

DEV void gload_lds16(const void* g, void* l) {
  __builtin_amdgcn_global_load_lds(
      (const __attribute__((address_space(1))) void*)g,
      (__attribute__((address_space(3))) void*)l, 16, 0, 0);
}

DEV f32x4 mfma16(bf16x8 a, bf16x8 b, f32x4 c) {
  return __builtin_amdgcn_mfma_f32_16x16x32_bf16(a, b, c, 0, 0, 0);
}

DEV u16 f2bf(float x) {
  return __builtin_bit_cast(u16, __float2bfloat16(x));
}

// ---------------- fp32 -> bf16 conversion (vectorized) ----------------
__global__ void __launch_bounds__(256) conv_f32_bf16(
    const float* __restrict__ in, u16* __restrict__ out) {
  const size_t i = ((size_t)blockIdx.x * 256 + threadIdx.x) * 4;
  const float4 v = *reinterpret_cast<const float4*>(in + i);
  ushort4 o;
  o.x = f2bf(v.x); o.y = f2bf(v.y); o.z = f2bf(v.z); o.w = f2bf(v.w);
  *reinterpret_cast<ushort4*>(out + i) = o;
}

// ---------------- GEMM: C[M][N] = A[M][K] @ B[N][K]^T + bias ----------
#define BM 128
#define BN 128
#define BK 32

__global__ void __launch_bounds__(256) gemm_bt(
    const u16* __restrict__ A, const u16* __restrict__ Bw,
    const float* __restrict__ bias, void* __restrict__ Cout,
    const int M, const int N, const int K, const int out_f32) {
  __shared__ u16 As[BM * BK];
  __shared__ u16 Bs[BN * BK];

  const int tid = threadIdx.x;
  const int lane = tid & 63;
  const int w = tid >> 6;
  const int wr = w >> 1, wc = w & 1;
  const int g = lane >> 4;
  const int r16 = lane & 15;
  const int m0 = blockIdx.x * BM, n0 = blockIdx.y * BN;

  const f32x4 zero = {0.f, 0.f, 0.f, 0.f};
  f32x4 acc[4][4];
#pragma unroll
  for (int i = 0; i < 4; ++i)
#pragma unroll
    for (int j = 0; j < 4; ++j) acc[i][j] = zero;

  const int srow = w * 16 + (lane >> 2);
  const int scol = (lane & 3) * 8;
  const u16* ga0 = A + (size_t)(m0 + srow) * K + scol;
  const u16* ga1 = A + (size_t)(m0 + 64 + srow) * K + scol;
  const u16* gb0 = Bw + (size_t)(n0 + srow) * K + scol;
  const u16* gb1 = Bw + (size_t)(n0 + 64 + srow) * K + scol;
  u16* la0 = &As[(w * 16) * BK];
  u16* la1 = &As[(64 + w * 16) * BK];
  u16* lb0 = &Bs[(w * 16) * BK];
  u16* lb1 = &Bs[(64 + w * 16) * BK];

  for (int kt = 0; kt < K; kt += BK) {
    gload_lds16(ga0 + kt, la0);
    gload_lds16(ga1 + kt, la1);
    gload_lds16(gb0 + kt, lb0);
    gload_lds16(gb1 + kt, lb1);
    __syncthreads();

    bf16x8 af[4], bf[4];
#pragma unroll
    for (int i = 0; i < 4; ++i) {
      af[i] = *reinterpret_cast<const bf16x8*>(
          &As[(wr * 64 + i * 16 + r16) * BK + g * 8]);
      bf[i] = *reinterpret_cast<const bf16x8*>(
          &Bs[(wc * 64 + i * 16 + r16) * BK + g * 8]);
    }
#pragma unroll
    for (int i = 0; i < 4; ++i)
#pragma unroll
      for (int j = 0; j < 4; ++j)
        acc[i][j] = mfma16(af[i], bf[j], acc[i][j]);
    __syncthreads();
  }

  const int cbase = n0 + wc * 64 + r16;
  const int rbase = m0 + wr * 64 + g * 4;
#pragma unroll
  for (int i = 0; i < 4; ++i) {
#pragma unroll
    for (int j = 0; j < 4; ++j) {
      const int c = cbase + j * 16;
      const float bv = bias[c];
#pragma unroll
      for (int r = 0; r < 4; ++r) {
        const float v = acc[i][j][r] + bv;
        const size_t idx = (size_t)(rbase + i * 16 + r) * N + c;
        if (out_f32) ((float*)Cout)[idx] = v;
        else ((u16*)Cout)[idx] = f2bf(v);
      }
    }
  }
}

// ---------------- causal flash attention ------------------------------
// QBLK=128 (4 waves x 32 rows), KBLK=64.
// Ks: [64][128] bf16, 16B-chunk XOR swizzle c' = c ^ (row&7), staged via
//   global_load_lds with pre-swizzled per-lane SOURCE (linear LDS dest).
// Vt: [128][64] bf16 transposed; writes b64 / reads b128, 16B-chunk
//   swizzle c' = c ^ ((d>>3)&7).
#define SEQ 2048
#define DMODEL 2048
#define DH 128
#define QBLK 128
#define KBLK 64
#define PLS 72  // P row stride (elems): 144B, 16B-aligned
#define C1 0.12751744f  // (1/sqrt(128)) * log2(e)

__global__ void __launch_bounds__(256) flash_attn(
    const u16* __restrict__ Qh, const u16* __restrict__ Kh,
    const u16* __restrict__ Vh, u16* __restrict__ O) {
  __shared__ u16 Ks[KBLK * DH];    // 16 KB
  __shared__ u16 Vt[DH * KBLK];    // 16 KB
  __shared__ u16 Pl[4][32 * PLS];  // 18 KB

  const int tid = threadIdx.x;
  const int lane = tid & 63;
  const int w = tid >> 6;
  const int g = lane >> 4;
  const int r16 = lane & 15;

  // scrambled qt for cross-CU causal load balance (bijective per (b,h))
  const int low = blockIdx.x & 15;
  const int bh = blockIdx.x >> 4;
  const int qt = low ^ (bh & 15);
  const int h = bh & 15;
  const int b = bh >> 4;
  const int q0 = qt * QBLK;
  const size_t rowbase = (size_t)b * SEQ;
  const int hoff = h * DH;

  // Q fragments in registers: 2 row-frags x 4 k-chunks
  bf16x8 aq[2][4];
#pragma unroll
  for (int ii = 0; ii < 2; ++ii) {
    const size_t qr = rowbase + q0 + w * 32 + ii * 16 + r16;
#pragma unroll
    for (int c = 0; c < 4; ++c)
      aq[ii][c] = *reinterpret_cast<const bf16x8*>(
          &Qh[qr * DMODEL + hoff + c * 32 + g * 8]);
  }

  const f32x4 zero = {0.f, 0.f, 0.f, 0.f};
  f32x4 oacc[2][8];
#pragma unroll
  for (int ii = 0; ii < 2; ++ii)
#pragma unroll
    for (int df = 0; df < 8; ++df) oacc[ii][df] = zero;
  float mrow[2][4], lrow[2][4];
#pragma unroll
  for (int ii = 0; ii < 2; ++ii)
#pragma unroll
    for (int j = 0; j < 4; ++j) { mrow[ii][j] = -1e30f; lrow[ii][j] = 0.f; }

  const int krl = w * 16 + (lane >> 4);  // K staging: lane's base row
  const int kg4 = w * 4 + (lane >> 4);   // V staging: 4-row group 0..15
  const int du = r16;                    // V staging: d-octet 0..15

  const int nkt = 2 * qt + 2;
  const int qw = q0 + w * 32;  // wave's first q row

  for (int kt = 0; kt < nkt; ++kt) {
    const int k0 = kt * KBLK;

    // V prefetch to regs (no LDS touch -> before barrier)
    uint4 vv[4];
#pragma unroll
    for (int r = 0; r < 4; ++r)
      vv[r] = *reinterpret_cast<const uint4*>(
          &Vh[(rowbase + k0 + kg4 * 4 + r) * DMODEL + hoff + du * 8]);

    __syncthreads();  // prev tile fully consumed

    // K DMA: linear LDS dest, source chunk pre-swizzled cg = cl ^ (row&7)
#pragma unroll
    for (int i = 0; i < 4; ++i) {
      const int r = krl + i * 4;
      const int cg = (lane & 15) ^ (r & 7);
      gload_lds16(&Kh[(rowbase + k0 + r) * DMODEL + hoff + cg * 8],
                  &Ks[(w * 16 + i * 4) * DH]);
    }

    // V transpose: 8x b64 swizzled writes per thread
#pragma unroll
    for (int j = 0; j < 8; ++j) {
      const int d = du * 8 + j;
      ushort4 pk;
      pk.x = ((const u16*)&vv[0])[j];
      pk.y = ((const u16*)&vv[1])[j];
      pk.z = ((const u16*)&vv[2])[j];
      pk.w = ((const u16*)&vv[3])[j];
      const int slot = (((kg4 >> 1) ^ (du & 7)) * 8) + (kg4 & 1) * 4;
      *reinterpret_cast<ushort4*>(&Vt[d * KBLK + slot]) = pk;
    }

    __syncthreads();

    // wave-level causal skip (k0 multiple of 64 => one condition per wave)
    if (k0 <= qw + 15) {
      const bool domask = (k0 + 63 > qw);

#pragma unroll
      for (int ii = 0; ii < 2; ++ii) {
        // S = Q K^T  (4 col-frags x 4 k-chunks)
        f32x4 sacc[4];
#pragma unroll
        for (int kf = 0; kf < 4; ++kf) sacc[kf] = zero;
#pragma unroll
        for (int kf = 0; kf < 4; ++kf) {
          const int row = kf * 16 + r16;
#pragma unroll
          for (int c = 0; c < 4; ++c) {
            const bf16x8 bk = *reinterpret_cast<const bf16x8*>(
                &Ks[row * DH + (((c * 4 + g) ^ (r16 & 7)) * 8)]);
            sacc[kf] = mfma16(aq[ii][c], bk, sacc[kf]);
          }
        }
        // online softmax; rows qbase+j, cols kf*16+r16
        const int qbase = qw + ii * 16 + g * 4;
#pragma unroll
        for (int j = 0; j < 4; ++j) {
          float sv0 = sacc[0][j], sv1 = sacc[1][j];
          float sv2 = sacc[2][j], sv3 = sacc[3][j];
          if (domask) {
            const int qr = qbase + j;
            if (k0 + r16 > qr) sv0 = -1e9f;
            if (k0 + 16 + r16 > qr) sv1 = -1e9f;
            if (k0 + 32 + r16 > qr) sv2 = -1e9f;
            if (k0 + 48 + r16 > qr) sv3 = -1e9f;
          }
          float mx = fmaxf(fmaxf(sv0, sv1), fmaxf(sv2, sv3));
          mx = fmaxf(mx, __shfl_xor(mx, 1));
          mx = fmaxf(mx, __shfl_xor(mx, 2));
          mx = fmaxf(mx, __shfl_xor(mx, 4));
          mx = fmaxf(mx, __shfl_xor(mx, 8));
          const float mold = mrow[ii][j];
          const float mnew = fmaxf(mold, mx);
          const float alpha = exp2f((mold - mnew) * C1);
          mrow[ii][j] = mnew;
          const float e0 = exp2f((sv0 - mnew) * C1);
          const float e1 = exp2f((sv1 - mnew) * C1);
          const float e2 = exp2f((sv2 - mnew) * C1);
          const float e3 = exp2f((sv3 - mnew) * C1);
          float rs = (e0 + e1) + (e2 + e3);
          rs += __shfl_xor(rs, 1);
          rs += __shfl_xor(rs, 2);
          rs += __shfl_xor(rs, 4);
          rs += __shfl_xor(rs, 8);
          lrow[ii][j] = lrow[ii][j] * alpha + rs;
#pragma unroll
          for (int df = 0; df < 8; ++df) oacc[ii][df][j] *= alpha;
          u16* pr = &Pl[w][(ii * 16 + g * 4 + j) * PLS];
          pr[r16] = f2bf(e0);
          pr[16 + r16] = f2bf(e1);
          pr[32 + r16] = f2bf(e2);
          pr[48 + r16] = f2bf(e3);
        }
      }

      // O += P V  (Vt b128 swizzled reads, shared across row-frags)
#pragma unroll
      for (int kb = 0; kb < 2; ++kb) {
        const bf16x8 pf0 = *reinterpret_cast<const bf16x8*>(
            &Pl[w][(r16) * PLS + kb * 32 + g * 8]);
        const bf16x8 pf1 = *reinterpret_cast<const bf16x8*>(
            &Pl[w][(16 + r16) * PLS + kb * 32 + g * 8]);
#pragma unroll
        for (int df = 0; df < 8; ++df) {
          const int d = df * 16 + r16;
          const int w3 = (df * 2 + (r16 >> 3)) & 7;
          const bf16x8 bv = *reinterpret_cast<const bf16x8*>(
              &Vt[d * KBLK + (((kb * 4 + g) ^ w3) * 8)]);
          oacc[0][df] = mfma16(pf0, bv, oacc[0][df]);
          oacc[1][df] = mfma16(pf1, bv, oacc[1][df]);
        }
      }
    }
  }

  // epilogue
#pragma unroll
  for (int ii = 0; ii < 2; ++ii) {
#pragma unroll
    for (int df = 0; df < 8; ++df) {
#pragma unroll
      for (int j = 0; j < 4; ++j) {
        const size_t q = rowbase + q0 + w * 32 + ii * 16 + g * 4 + j;
        O[q * DMODEL + hoff + df * 16 + r16] =
            f2bf(oacc[ii][df][j] / lrow[ii][j]);
      }
    }
  }
}

// ---------------- launcher --------------------------------------------
extern "C" void kernel_launch(void* const* d_in, const int* in_sizes, int n_in,
                              void* d_out, int out_size, void* d_ws,
                              size_t ws_size, hipStream_t stream) {
  const int Bv = 2, S = 2048, D = 2048;
  const int M = Bv * S;
  const size_t NT = (size_t)M * D;
  const size_t NW = (size_t)D * D;

  const float* q = (const float*)d_in[0];
  const float* k = (const float*)d_in[1];
  const float* v = (const float*)d_in[2];
  const float* wq_w = (const float*)d_in[4];
  const float* wq_b = (const float*)d_in[5];
  const float* wk_w = (const float*)d_in[6];
  const float* wk_b = (const float*)d_in[7];
  const float* wv_w = (const float*)d_in[8];
  const float* wv_b = (const float*)d_in[9];
  const float* dw = (const float*)d_in[10];
  const float* db = (const float*)d_in[11];
  float* out = (float*)d_out;

  char* ws = (char*)d_ws;
  u16* Xbf = (u16*)ws;
  u16* Wbf = (u16*)(ws + NT * 2);
  u16* Qh = (u16*)(ws + NT * 2 + NW * 2);
  u16* Kh = Qh + NT;
  u16* Vh = Kh + NT;
  u16* Obf = Vh + NT;

  const dim3 blk(256);
  const dim3 gact((unsigned)(NT / 1024));
  const dim3 gw((unsigned)(NW / 1024));
  const dim3 ggemm(M / BM, D / BN);
  const dim3 gattn(Bv * 16 * (S / QBLK));  // 512

  conv_f32_bf16<<<gact, blk, 0, stream>>>(q, Xbf);
  conv_f32_bf16<<<gw, blk, 0, stream>>>(wq_w, Wbf);
  gemm_bt<<<ggemm, blk, 0, stream>>>(Xbf, Wbf, wq_b, Qh, M, D, D, 0);
  conv_f32_bf16<<<gact, blk, 0, stream>>>(k, Xbf);
  conv_f32_bf16<<<gw, blk, 0, stream>>>(wk_w, Wbf);
  gemm_bt<<<ggemm, blk, 0, stream>>>(Xbf, Wbf, wk_b, Kh, M, D, D, 0);
  conv_f32_bf16<<<gact, blk, 0, stream>>>(v, Xbf);
  conv_f32_bf16<<<gw, blk, 0, stream>>>(wv_w, Wbf);
  gemm_bt<<<ggemm, blk, 0, stream>>>(Xbf, Wbf, wv_b, Vh, M, D, D, 0);
  flash_attn<<<gattn, blk, 0, stream>>>(Qh, Kh, Vh, Obf);
  conv_f32_bf16<<<gw, blk, 0, stream>>>(dw, Wbf);
  gemm_bt<<<ggemm, blk, 0, stream>>>(Obf, Wbf, db, out, M, D, D, 1);
}

// Round 3
// 445.424 us; speedup vs baseline: 1.7091x; 1.2323x over previous
//
#include <hip/hip_runtime.h>
#include <hip/hip_bf16.h>

// GPT3 attention block, B=2 S=2048 D=2048 H=16 Dh=128.
// bf16 MFMA GEMMs + flash attention (QBLK=64, balanced grid, swizzled LDS).

typedef __bf16 bf16x8 __attribute__((ext_vector_type(8)));
typedef float f32x4 __attribute__((ext_vector_type(4)));
typedef unsigned short u16;

#define DEV static __device__ __forceinline__

DEV void gload_lds16(const void* g, void* l) {
  __builtin_amdgcn_global_load_lds(
      (const __attribute__((address_space(1))) void*)g,
      (__attribute__((address_space(3))) void*)l, 16, 0, 0);
}

DEV f32x4 mfma16(bf16x8 a, bf16x8 b, f32x4 c) {
  return __builtin_amdgcn_mfma_f32_16x16x32_bf16(a, b, c, 0, 0, 0);
}

DEV u16 f2bf(float x) {
  return __builtin_bit_cast(u16, __float2bfloat16(x));
}

// ---------------- fp32 -> bf16 conversion (vectorized) ----------------
__global__ void __launch_bounds__(256) conv_f32_bf16(
    const float* __restrict__ in, u16* __restrict__ out) {
  const size_t i = ((size_t)blockIdx.x * 256 + threadIdx.x) * 4;
  const float4 v = *reinterpret_cast<const float4*>(in + i);
  ushort4 o;
  o.x = f2bf(v.x); o.y = f2bf(v.y); o.z = f2bf(v.z); o.w = f2bf(v.w);
  *reinterpret_cast<ushort4*>(out + i) = o;
}

// ---------------- GEMM: C[M][N] = A[M][K] @ B[N][K]^T + bias ----------
#define BM 128
#define BN 128
#define BK 32

__global__ void __launch_bounds__(256) gemm_bt(
    const u16* __restrict__ A, const u16* __restrict__ Bw,
    const float* __restrict__ bias, void* __restrict__ Cout,
    const int M, const int N, const int K, const int out_f32) {
  __shared__ u16 As[BM * BK];
  __shared__ u16 Bs[BN * BK];

  const int tid = threadIdx.x;
  const int lane = tid & 63;
  const int w = tid >> 6;
  const int wr = w >> 1, wc = w & 1;
  const int g = lane >> 4;
  const int r16 = lane & 15;
  const int m0 = blockIdx.x * BM, n0 = blockIdx.y * BN;

  const f32x4 zero = {0.f, 0.f, 0.f, 0.f};
  f32x4 acc[4][4];
#pragma unroll
  for (int i = 0; i < 4; ++i)
#pragma unroll
    for (int j = 0; j < 4; ++j) acc[i][j] = zero;

  const int srow = w * 16 + (lane >> 2);
  const int scol = (lane & 3) * 8;
  const u16* ga0 = A + (size_t)(m0 + srow) * K + scol;
  const u16* ga1 = A + (size_t)(m0 + 64 + srow) * K + scol;
  const u16* gb0 = Bw + (size_t)(n0 + srow) * K + scol;
  const u16* gb1 = Bw + (size_t)(n0 + 64 + srow) * K + scol;
  u16* la0 = &As[(w * 16) * BK];
  u16* la1 = &As[(64 + w * 16) * BK];
  u16* lb0 = &Bs[(w * 16) * BK];
  u16* lb1 = &Bs[(64 + w * 16) * BK];

  for (int kt = 0; kt < K; kt += BK) {
    gload_lds16(ga0 + kt, la0);
    gload_lds16(ga1 + kt, la1);
    gload_lds16(gb0 + kt, lb0);
    gload_lds16(gb1 + kt, lb1);
    __syncthreads();

    bf16x8 af[4], bf[4];
#pragma unroll
    for (int i = 0; i < 4; ++i) {
      af[i] = *reinterpret_cast<const bf16x8*>(
          &As[(wr * 64 + i * 16 + r16) * BK + g * 8]);
      bf[i] = *reinterpret_cast<const bf16x8*>(
          &Bs[(wc * 64 + i * 16 + r16) * BK + g * 8]);
    }
#pragma unroll
    for (int i = 0; i < 4; ++i)
#pragma unroll
      for (int j = 0; j < 4; ++j)
        acc[i][j] = mfma16(af[i], bf[j], acc[i][j]);
    __syncthreads();
  }

  const int cbase = n0 + wc * 64 + r16;
  const int rbase = m0 + wr * 64 + g * 4;
#pragma unroll
  for (int i = 0; i < 4; ++i) {
#pragma unroll
    for (int j = 0; j < 4; ++j) {
      const int c = cbase + j * 16;
      const float bv = bias[c];
#pragma unroll
      for (int r = 0; r < 4; ++r) {
        const float v = acc[i][j][r] + bv;
        const size_t idx = (size_t)(rbase + i * 16 + r) * N + c;
        if (out_f32) ((float*)Cout)[idx] = v;
        else ((u16*)Cout)[idx] = f2bf(v);
      }
    }
  }
}

// ---------------- causal flash attention ------------------------------
// QBLK=64 (4 waves x 16 rows), KBLK=64, 1024 blocks (b,h,qt scrambled).
// nkt = qt+1 exact; mask only on diagonal tile kt==qt.
// Ks: [64][128] 16B-chunk XOR swizzle c'=c^(row&7) via pre-swizzled
//   global_load_lds source. Vt: [128][64] transposed, swizzled b64 writes /
//   b128 reads. V rows prefetched to regs one tile ahead (issued at compute
//   start, hidden under MFMA/softmax).
#define SEQ 2048
#define DMODEL 2048
#define DH 128
#define QBLK 64
#define KBLK 64
#define PLS 72        // P row stride (elems)
#define C1 0.12751744f       // (1/sqrt(128)) * log2(e)
#define THR_RAW 62.73f       // defer-max threshold: 8 / C1 (raw logit units)

__global__ void __launch_bounds__(256) flash_attn(
    const u16* __restrict__ Qh, const u16* __restrict__ Kh,
    const u16* __restrict__ Vh, u16* __restrict__ O) {
  __shared__ u16 Ks[KBLK * DH];    // 16 KB
  __shared__ u16 Vt[DH * KBLK];    // 16 KB
  __shared__ u16 Pl[4][16 * PLS];  // 9 KB

  const int tid = threadIdx.x;
  const int lane = tid & 63;
  const int w = tid >> 6;
  const int g = lane >> 4;
  const int r16 = lane & 15;

  // scrambled qt across block index for dispatch-time load balance
  const int bh = blockIdx.x >> 5;          // 0..31
  const int qt = (blockIdx.x & 31) ^ bh;   // bijective per bh
  const int h = bh & 15;
  const int b = bh >> 4;
  const int q0 = qt * QBLK;
  const size_t rowbase = (size_t)b * SEQ;
  const int hoff = h * DH;
  const int qw = q0 + w * 16;

  // Q fragments in registers: 4 k-chunks
  bf16x8 aq[4];
  {
    const size_t qr = rowbase + qw + r16;
#pragma unroll
    for (int c = 0; c < 4; ++c)
      aq[c] = *reinterpret_cast<const bf16x8*>(
          &Qh[qr * DMODEL + hoff + c * 32 + g * 8]);
  }

  const f32x4 zero = {0.f, 0.f, 0.f, 0.f};
  f32x4 oacc[8];
#pragma unroll
  for (int df = 0; df < 8; ++df) oacc[df] = zero;
  float mrow[4] = {-1e30f, -1e30f, -1e30f, -1e30f};
  float lrow[4] = {0.f, 0.f, 0.f, 0.f};

  const int krl = w * 16 + g;   // K staging base row for this lane
  const int kg4 = w * 4 + g;    // V staging 4-row group
  const int du = r16;           // V staging d-octet

  const int nkt = qt + 1;

  // V(0) prefetch (exposed once)
  uint4 vv[4];
#pragma unroll
  for (int r = 0; r < 4; ++r)
    vv[r] = *reinterpret_cast<const uint4*>(
        &Vh[(rowbase + kg4 * 4 + r) * DMODEL + hoff + du * 8]);

  for (int kt = 0; kt < nkt; ++kt) {
    const int k0 = kt * KBLK;
    __syncthreads();  // prev tile fully consumed

    // K DMA: linear LDS dest, source chunk pre-swizzled
#pragma unroll
    for (int i = 0; i < 4; ++i) {
      const int r = krl + i * 4;
      const int cg = r16 ^ (r & 7);
      gload_lds16(&Kh[(rowbase + k0 + r) * DMODEL + hoff + cg * 8],
                  &Ks[(w * 16 + i * 4) * DH]);
    }

    // V transpose from regs: 8x b64 swizzled writes
#pragma unroll
    for (int j = 0; j < 8; ++j) {
      const int d = du * 8 + j;
      ushort4 pk;
      pk.x = ((const u16*)&vv[0])[j];
      pk.y = ((const u16*)&vv[1])[j];
      pk.z = ((const u16*)&vv[2])[j];
      pk.w = ((const u16*)&vv[3])[j];
      const int slot = (((kg4 >> 1) ^ (du & 7)) * 8) + (kg4 & 1) * 4;
      *reinterpret_cast<ushort4*>(&Vt[d * KBLK + slot]) = pk;
    }

    __syncthreads();  // drains K DMA + Vt writes

    // prefetch next tile's V rows (hidden under compute)
    if (kt + 1 < nkt) {
#pragma unroll
      for (int r = 0; r < 4; ++r)
        vv[r] = *reinterpret_cast<const uint4*>(
            &Vh[(rowbase + k0 + KBLK + kg4 * 4 + r) * DMODEL + hoff + du * 8]);
    }

    // S = Q K^T
    f32x4 sacc[4];
#pragma unroll
    for (int kf = 0; kf < 4; ++kf) sacc[kf] = zero;
#pragma unroll
    for (int kf = 0; kf < 4; ++kf) {
      const int row = kf * 16 + r16;
#pragma unroll
      for (int c = 0; c < 4; ++c) {
        const bf16x8 bk = *reinterpret_cast<const bf16x8*>(
            &Ks[row * DH + (((c * 4 + g) ^ (r16 & 7)) * 8)]);
        sacc[kf] = mfma16(aq[c], bk, sacc[kf]);
      }
    }

    // online softmax with defer-max
    const bool domask = (kt == qt);
    float sv[4][4];
    float mx[4];
    bool need = false;
#pragma unroll
    for (int j = 0; j < 4; ++j) {
      float a0 = sacc[0][j], a1 = sacc[1][j];
      float a2 = sacc[2][j], a3 = sacc[3][j];
      if (domask) {
        const int qr = qw + g * 4 + j;
        if (k0 + r16 > qr) a0 = -1e9f;
        if (k0 + 16 + r16 > qr) a1 = -1e9f;
        if (k0 + 32 + r16 > qr) a2 = -1e9f;
        if (k0 + 48 + r16 > qr) a3 = -1e9f;
      }
      sv[0][j] = a0; sv[1][j] = a1; sv[2][j] = a2; sv[3][j] = a3;
      float m = fmaxf(fmaxf(a0, a1), fmaxf(a2, a3));
      m = fmaxf(m, __shfl_xor(m, 1));
      m = fmaxf(m, __shfl_xor(m, 2));
      m = fmaxf(m, __shfl_xor(m, 4));
      m = fmaxf(m, __shfl_xor(m, 8));
      mx[j] = m;
      need |= (m > mrow[j] + THR_RAW);
    }
    if (__any((int)need)) {
#pragma unroll
      for (int j = 0; j < 4; ++j) {
        const float mn = fmaxf(mrow[j], mx[j]);
        const float al = exp2f((mrow[j] - mn) * C1);
        mrow[j] = mn;
        lrow[j] *= al;
#pragma unroll
        for (int df = 0; df < 8; ++df) oacc[df][j] *= al;
      }
    }
#pragma unroll
    for (int j = 0; j < 4; ++j) {
      const float e0 = exp2f((sv[0][j] - mrow[j]) * C1);
      const float e1 = exp2f((sv[1][j] - mrow[j]) * C1);
      const float e2 = exp2f((sv[2][j] - mrow[j]) * C1);
      const float e3 = exp2f((sv[3][j] - mrow[j]) * C1);
      u16* pr = &Pl[w][(g * 4 + j) * PLS];
      pr[r16] = f2bf(e0);
      pr[16 + r16] = f2bf(e1);
      pr[32 + r16] = f2bf(e2);
      pr[48 + r16] = f2bf(e3);
      float rs = (e0 + e1) + (e2 + e3);
      rs += __shfl_xor(rs, 1);
      rs += __shfl_xor(rs, 2);
      rs += __shfl_xor(rs, 4);
      rs += __shfl_xor(rs, 8);
      lrow[j] += rs;
    }

    // O += P V
#pragma unroll
    for (int kb = 0; kb < 2; ++kb) {
      const bf16x8 pf = *reinterpret_cast<const bf16x8*>(
          &Pl[w][r16 * PLS + kb * 32 + g * 8]);
#pragma unroll
      for (int df = 0; df < 8; ++df) {
        const int d = df * 16 + r16;
        const int w3 = (df * 2 + (r16 >> 3)) & 7;
        const bf16x8 bv = *reinterpret_cast<const bf16x8*>(
            &Vt[d * KBLK + (((kb * 4 + g) ^ w3) * 8)]);
        oacc[df] = mfma16(pf, bv, oacc[df]);
      }
    }
  }

  // epilogue
  float linv[4];
#pragma unroll
  for (int j = 0; j < 4; ++j) linv[j] = __builtin_amdgcn_rcpf(lrow[j]);
#pragma unroll
  for (int df = 0; df < 8; ++df) {
#pragma unroll
    for (int j = 0; j < 4; ++j) {
      const size_t q = rowbase + qw + g * 4 + j;
      O[q * DMODEL + hoff + df * 16 + r16] = f2bf(oacc[df][j] * linv[j]);
    }
  }
}

// ---------------- launcher --------------------------------------------
extern "C" void kernel_launch(void* const* d_in, const int* in_sizes, int n_in,
                              void* d_out, int out_size, void* d_ws,
                              size_t ws_size, hipStream_t stream) {
  const int Bv = 2, S = 2048, D = 2048;
  const int M = Bv * S;
  const size_t NT = (size_t)M * D;
  const size_t NW = (size_t)D * D;

  const float* q = (const float*)d_in[0];
  const float* k = (const float*)d_in[1];
  const float* v = (const float*)d_in[2];
  const float* wq_w = (const float*)d_in[4];
  const float* wq_b = (const float*)d_in[5];
  const float* wk_w = (const float*)d_in[6];
  const float* wk_b = (const float*)d_in[7];
  const float* wv_w = (const float*)d_in[8];
  const float* wv_b = (const float*)d_in[9];
  const float* dw = (const float*)d_in[10];
  const float* db = (const float*)d_in[11];
  float* out = (float*)d_out;

  char* ws = (char*)d_ws;
  u16* Xbf = (u16*)ws;
  u16* Wbf = (u16*)(ws + NT * 2);
  u16* Qh = (u16*)(ws + NT * 2 + NW * 2);
  u16* Kh = Qh + NT;
  u16* Vh = Kh + NT;
  u16* Obf = Vh + NT;

  const dim3 blk(256);
  const dim3 gact((unsigned)(NT / 1024));
  const dim3 gw((unsigned)(NW / 1024));
  const dim3 ggemm(M / BM, D / BN);
  const dim3 gattn(Bv * 16 * (S / QBLK));  // 1024

  conv_f32_bf16<<<gact, blk, 0, stream>>>(q, Xbf);
  conv_f32_bf16<<<gw, blk, 0, stream>>>(wq_w, Wbf);
  gemm_bt<<<ggemm, blk, 0, stream>>>(Xbf, Wbf, wq_b, Qh, M, D, D, 0);
  conv_f32_bf16<<<gact, blk, 0, stream>>>(k, Xbf);
  conv_f32_bf16<<<gw, blk, 0, stream>>>(wk_w, Wbf);
  gemm_bt<<<ggemm, blk, 0, stream>>>(Xbf, Wbf, wk_b, Kh, M, D, D, 0);
  conv_f32_bf16<<<gact, blk, 0, stream>>>(v, Xbf);
  conv_f32_bf16<<<gw, blk, 0, stream>>>(wv_w, Wbf);
  gemm_bt<<<ggemm, blk, 0, stream>>>(Xbf, Wbf, wv_b, Vh, M, D, D, 0);
  flash_attn<<<gattn, blk, 0, stream>>>(Qh, Kh, Vh, Obf);
  conv_f32_bf16<<<gw, blk, 0, stream>>>(dw, Wbf);
  gemm_bt<<<ggemm, blk, 0, stream>>>(Obf, Wbf, db, out, M, D, D, 1);
}

// Round 4
// 393.819 us; speedup vs baseline: 1.9331x; 1.1310x over previous
//
#include <hip/hip_runtime.h>
#include <hip/hip_bf16.h>

// GPT3 attention block, B=2 S=2048 D=2048 H=16 Dh=128.
// bf16 MFMA GEMMs + swapped-QK^T 32x32 flash attention (in-register softmax).

typedef __bf16 bf16x8 __attribute__((ext_vector_type(8)));
typedef float f32x4 __attribute__((ext_vector_type(4)));
typedef float f32x16 __attribute__((ext_vector_type(16)));
typedef unsigned short u16;
typedef unsigned int u32;

#define DEV static __device__ __forceinline__

DEV void gload_lds16(const void* g, void* l) {
  __builtin_amdgcn_global_load_lds(
      (const __attribute__((address_space(1))) void*)g,
      (__attribute__((address_space(3))) void*)l, 16, 0, 0);
}

DEV f32x4 mfma16(bf16x8 a, bf16x8 b, f32x4 c) {
  return __builtin_amdgcn_mfma_f32_16x16x32_bf16(a, b, c, 0, 0, 0);
}

DEV f32x16 mfma32(bf16x8 a, bf16x8 b, f32x16 c) {
  return __builtin_amdgcn_mfma_f32_32x32x16_bf16(a, b, c, 0, 0, 0);
}

DEV u16 f2bf(float x) {
  return __builtin_bit_cast(u16, __float2bfloat16(x));
}

DEV u32 pack2(float lo, float hi_) {
  return (u32)f2bf(lo) | ((u32)f2bf(hi_) << 16);
}

// ---------------- fp32 -> bf16 conversion (vectorized) ----------------
__global__ void __launch_bounds__(256) conv_f32_bf16(
    const float* __restrict__ in, u16* __restrict__ out) {
  const size_t i = ((size_t)blockIdx.x * 256 + threadIdx.x) * 4;
  const float4 v = *reinterpret_cast<const float4*>(in + i);
  ushort4 o;
  o.x = f2bf(v.x); o.y = f2bf(v.y); o.z = f2bf(v.z); o.w = f2bf(v.w);
  *reinterpret_cast<ushort4*>(out + i) = o;
}

// ---------------- GEMM: C[M][N] = A[M][K] @ B[N][K]^T + bias ----------
#define BM 128
#define BN 128
#define BK 32

__global__ void __launch_bounds__(256) gemm_bt(
    const u16* __restrict__ A, const u16* __restrict__ Bw,
    const float* __restrict__ bias, void* __restrict__ Cout,
    const int M, const int N, const int K, const int out_f32) {
  __shared__ u16 As[BM * BK];
  __shared__ u16 Bs[BN * BK];

  const int tid = threadIdx.x;
  const int lane = tid & 63;
  const int w = tid >> 6;
  const int wr = w >> 1, wc = w & 1;
  const int g = lane >> 4;
  const int r16 = lane & 15;
  const int m0 = blockIdx.x * BM, n0 = blockIdx.y * BN;

  const f32x4 zero = {0.f, 0.f, 0.f, 0.f};
  f32x4 acc[4][4];
#pragma unroll
  for (int i = 0; i < 4; ++i)
#pragma unroll
    for (int j = 0; j < 4; ++j) acc[i][j] = zero;

  const int srow = w * 16 + (lane >> 2);
  const int scol = (lane & 3) * 8;
  const u16* ga0 = A + (size_t)(m0 + srow) * K + scol;
  const u16* ga1 = A + (size_t)(m0 + 64 + srow) * K + scol;
  const u16* gb0 = Bw + (size_t)(n0 + srow) * K + scol;
  const u16* gb1 = Bw + (size_t)(n0 + 64 + srow) * K + scol;
  u16* la0 = &As[(w * 16) * BK];
  u16* la1 = &As[(64 + w * 16) * BK];
  u16* lb0 = &Bs[(w * 16) * BK];
  u16* lb1 = &Bs[(64 + w * 16) * BK];

  for (int kt = 0; kt < K; kt += BK) {
    gload_lds16(ga0 + kt, la0);
    gload_lds16(ga1 + kt, la1);
    gload_lds16(gb0 + kt, lb0);
    gload_lds16(gb1 + kt, lb1);
    __syncthreads();

    bf16x8 af[4], bf[4];
#pragma unroll
    for (int i = 0; i < 4; ++i) {
      af[i] = *reinterpret_cast<const bf16x8*>(
          &As[(wr * 64 + i * 16 + r16) * BK + g * 8]);
      bf[i] = *reinterpret_cast<const bf16x8*>(
          &Bs[(wc * 64 + i * 16 + r16) * BK + g * 8]);
    }
#pragma unroll
    for (int i = 0; i < 4; ++i)
#pragma unroll
      for (int j = 0; j < 4; ++j)
        acc[i][j] = mfma16(af[i], bf[j], acc[i][j]);
    __syncthreads();
  }

  const int cbase = n0 + wc * 64 + r16;
  const int rbase = m0 + wr * 64 + g * 4;
#pragma unroll
  for (int i = 0; i < 4; ++i) {
#pragma unroll
    for (int j = 0; j < 4; ++j) {
      const int c = cbase + j * 16;
      const float bv = bias[c];
#pragma unroll
      for (int r = 0; r < 4; ++r) {
        const float v = acc[i][j][r] + bv;
        const size_t idx = (size_t)(rbase + i * 16 + r) * N + c;
        if (out_f32) ((float*)Cout)[idx] = v;
        else ((u16*)Cout)[idx] = f2bf(v);
      }
    }
  }
}

// ---------------- causal flash attention (swapped QK^T, 32x32) --------
// Block: 4 waves x 32 q-rows (QBLK=128), KBLK=64, 512 blocks.
// S^T = mfma32(K_frag, Q_frag): lane holds col q=lane&31, rows
//   k=(reg&3)+8*(reg>>2)+4*hi. Softmax in-register (per-lane scalar m,l).
// P->A-frag redistribution: bf16 packs + shfl_xor(32) + cndmask.
// Ks [64][128]: 16B-chunk XOR swizzle c'=c^(row&15), staged via
//   pre-swizzled global_load_lds source. Vt [128][64] transposed, octet
//   swizzle o'=o^((d>>2)&7), b64 writes / b128 reads.
#define SEQ 2048
#define DMODEL 2048
#define DH 128
#define QBLK 128
#define KBLK 64
#define C1 0.12751744f   // (1/sqrt(128)) * log2(e)
#define THR_RAW 62.73f   // defer-max threshold: 8 / C1

__global__ void __launch_bounds__(256, 2) flash_attn(
    const u16* __restrict__ Qh, const u16* __restrict__ Kh,
    const u16* __restrict__ Vh, u16* __restrict__ O) {
  __shared__ u16 Ks[KBLK * DH];  // 16 KB
  __shared__ u16 Vt[DH * KBLK];  // 16 KB

  const int tid = threadIdx.x;
  const int lane = tid & 63;
  const int w = tid >> 6;
  const int hi = lane >> 5;    // 0/1
  const int l31 = lane & 31;

  // scrambled qt for dispatch-time causal load balance
  const int bh = blockIdx.x >> 4;          // 0..31
  const int qt = (blockIdx.x & 15) ^ (bh & 15);
  const int h = bh & 15;
  const int b = bh >> 4;
  const int q0 = qt * QBLK;
  const size_t rowbase = (size_t)b * SEQ;
  const int hoff = h * DH;
  const int qw = q0 + w * 32;
  const int qlane = qw + l31;

  // Q fragments (B-operand): lane: col q=l31, dims c*16 + hi*8 + e
  bf16x8 aq[8];
  {
    const u16* qp = &Qh[(rowbase + qlane) * DMODEL + hoff + hi * 8];
#pragma unroll
    for (int c = 0; c < 8; ++c)
      aq[c] = *reinterpret_cast<const bf16x8*>(qp + c * 16);
  }

  f32x16 oacc[4];
#pragma unroll
  for (int dt = 0; dt < 4; ++dt)
#pragma unroll
    for (int r = 0; r < 16; ++r) oacc[dt][r] = 0.f;
  float mrow = -1e30f, lrow = 0.f;

  const int krl = w * 16 + (lane >> 4);  // K staging base row
  const int kg4 = w * 4 + (lane >> 4);   // V staging 4-row k group
  const int du = lane & 15;              // V staging d-octet

  const int nkt = 2 * qt + 2;
  const int ktd = qw >> 6;  // wave's diagonal k-tile

  // V(0) prefetch
  uint4 vv[4];
#pragma unroll
  for (int r = 0; r < 4; ++r)
    vv[r] = *reinterpret_cast<const uint4*>(
        &Vh[(rowbase + kg4 * 4 + r) * DMODEL + hoff + du * 8]);

  for (int kt = 0; kt < nkt; ++kt) {
    const int k0 = kt * KBLK;
    __syncthreads();  // prev tile fully consumed

    // K DMA: linear LDS dest, source 16B-chunk pre-swizzled ^(row&15)
#pragma unroll
    for (int i = 0; i < 4; ++i) {
      const int r = krl + i * 4;
      const int cg = (lane & 15) ^ (r & 15);
      gload_lds16(&Kh[(rowbase + k0 + r) * DMODEL + hoff + cg * 8],
                  &Ks[(w * 16 + i * 4) * DH]);
    }

    // V transpose from regs: 8x b64 swizzled writes
#pragma unroll
    for (int j = 0; j < 8; ++j) {
      const int d = du * 8 + j;
      ushort4 pk4;
      pk4.x = ((const u16*)&vv[0])[j];
      pk4.y = ((const u16*)&vv[1])[j];
      pk4.z = ((const u16*)&vv[2])[j];
      pk4.w = ((const u16*)&vv[3])[j];
      const int slot = (((kg4 >> 1) ^ ((d >> 2) & 7)) * 8) + (kg4 & 1) * 4;
      *reinterpret_cast<ushort4*>(&Vt[d * KBLK + slot]) = pk4;
    }

    __syncthreads();  // drains K DMA + Vt writes

    // prefetch next tile's V rows (hidden under compute)
    if (kt + 1 < nkt) {
#pragma unroll
      for (int r = 0; r < 4; ++r)
        vv[r] = *reinterpret_cast<const uint4*>(
            &Vh[(rowbase + k0 + KBLK + kg4 * 4 + r) * DMODEL + hoff + du * 8]);
    }

    if (kt > ktd) continue;  // wave-uniform causal skip (stage-only tile)

    const bool diag = (kt == ktd);
    const bool act1 = (kt < ktd) || (w & 1);  // subtile 1 active?
    const bool m0q = diag && !(w & 1);        // mask subtile 0
    const bool m1q = diag && (w & 1);         // mask subtile 1

    // S^T = K Q^T per 32-k subtile
    float p[2][16];
    {
      f32x16 s;
#pragma unroll
      for (int r = 0; r < 16; ++r) s[r] = 0.f;
#pragma unroll
      for (int c = 0; c < 8; ++c) {
        const int row = l31;
        const bf16x8 kf = *reinterpret_cast<const bf16x8*>(
            &Ks[row * DH + (((c * 2 + hi) ^ (row & 15)) * 8)]);
        s = mfma32(kf, aq[c], s);
      }
#pragma unroll
      for (int r = 0; r < 16; ++r) {
        const int krow = (r & 3) + 8 * (r >> 2) + 4 * hi;
        p[0][r] = (m0q && (k0 + krow > qlane)) ? -1e9f : s[r];
      }
    }
    if (act1) {
      f32x16 s;
#pragma unroll
      for (int r = 0; r < 16; ++r) s[r] = 0.f;
#pragma unroll
      for (int c = 0; c < 8; ++c) {
        const int row = 32 + l31;
        const bf16x8 kf = *reinterpret_cast<const bf16x8*>(
            &Ks[row * DH + (((c * 2 + hi) ^ (row & 15)) * 8)]);
        s = mfma32(kf, aq[c], s);
      }
#pragma unroll
      for (int r = 0; r < 16; ++r) {
        const int krow = (r & 3) + 8 * (r >> 2) + 4 * hi;
        p[1][r] = (m1q && (k0 + 32 + krow > qlane)) ? -1e9f : s[r];
      }
    } else {
#pragma unroll
      for (int r = 0; r < 16; ++r) p[1][r] = -1e9f;
    }

    // row max: in-lane tree + one cross-half exchange
    float mx = fmaxf(p[0][0], p[0][1]);
#pragma unroll
    for (int r = 2; r < 16; ++r) mx = fmaxf(mx, p[0][r]);
#pragma unroll
    for (int r = 0; r < 16; ++r) mx = fmaxf(mx, p[1][r]);
    mx = fmaxf(mx, __shfl_xor(mx, 32));

    const bool need = (mx > mrow + THR_RAW);
    if (__any((int)need)) {
      const float mn = fmaxf(mrow, mx);
      const float al = exp2f((mrow - mn) * C1);
      mrow = mn;
      lrow *= al;
#pragma unroll
      for (int r = 0; r < 16; ++r) {
        const float ar = __shfl(al, (r & 3) + 8 * (r >> 2) + 4 * hi);
#pragma unroll
        for (int dt = 0; dt < 4; ++dt) oacc[dt][r] *= ar;
      }
    }

    // exps + row sum
    float sum = 0.f;
#pragma unroll
    for (int t = 0; t < 2; ++t)
#pragma unroll
      for (int r = 0; r < 16; ++r) {
        p[t][r] = exp2f((p[t][r] - mrow) * C1);
        sum += p[t][r];
      }
    sum += __shfl_xor(sum, 32);
    lrow += sum;

    // pack to bf16 pairs
    u32 pk[2][8];
#pragma unroll
    for (int t = 0; t < 2; ++t)
#pragma unroll
      for (int m = 0; m < 8; ++m)
        pk[t][m] = pack2(p[t][2 * m], p[t][2 * m + 1]);

    // PV: per 16-k slice build A-frag via shfl_xor(32) + select
#pragma unroll
    for (int ks = 0; ks < 4; ++ks) {
      if (ks >= 2 && !act1) break;
      const int t = ks >> 1;
      const int bs = (ks & 1) * 4;
      const u32 s0 = __shfl_xor(pk[t][bs + 0], 32);
      const u32 s1 = __shfl_xor(pk[t][bs + 1], 32);
      const u32 s2 = __shfl_xor(pk[t][bs + 2], 32);
      const u32 s3 = __shfl_xor(pk[t][bs + 3], 32);
      union { u32 u[4]; bf16x8 v; } pa;
      pa.u[0] = hi ? s2 : pk[t][bs + 0];
      pa.u[1] = hi ? s3 : pk[t][bs + 1];
      pa.u[2] = hi ? pk[t][bs + 2] : s0;
      pa.u[3] = hi ? pk[t][bs + 3] : s1;
#pragma unroll
      for (int dt = 0; dt < 4; ++dt) {
        const int d = dt * 32 + l31;
        const bf16x8 vf = *reinterpret_cast<const bf16x8*>(
            &Vt[d * KBLK + (((ks * 2 + hi) ^ ((d >> 2) & 7)) * 8)]);
        oacc[dt] = mfma32(pa.v, vf, oacc[dt]);
      }
    }
  }

  // epilogue: O[q][d], oacc row=q (reg map), col=d
  const float li = __builtin_amdgcn_rcpf(lrow);
#pragma unroll
  for (int r = 0; r < 16; ++r) {
    const int rowq = (r & 3) + 8 * (r >> 2) + 4 * hi;
    const float lr = __shfl(li, rowq);
    u16* op = &O[(rowbase + qw + rowq) * DMODEL + hoff + l31];
#pragma unroll
    for (int dt = 0; dt < 4; ++dt) op[dt * 32] = f2bf(oacc[dt][r] * lr);
  }
}

// ---------------- launcher --------------------------------------------
extern "C" void kernel_launch(void* const* d_in, const int* in_sizes, int n_in,
                              void* d_out, int out_size, void* d_ws,
                              size_t ws_size, hipStream_t stream) {
  const int Bv = 2, S = 2048, D = 2048;
  const int M = Bv * S;
  const size_t NT = (size_t)M * D;
  const size_t NW = (size_t)D * D;

  const float* q = (const float*)d_in[0];
  const float* k = (const float*)d_in[1];
  const float* v = (const float*)d_in[2];
  const float* wq_w = (const float*)d_in[4];
  const float* wq_b = (const float*)d_in[5];
  const float* wk_w = (const float*)d_in[6];
  const float* wk_b = (const float*)d_in[7];
  const float* wv_w = (const float*)d_in[8];
  const float* wv_b = (const float*)d_in[9];
  const float* dw = (const float*)d_in[10];
  const float* db = (const float*)d_in[11];
  float* out = (float*)d_out;

  char* ws = (char*)d_ws;
  u16* Xbf = (u16*)ws;
  u16* Wbf = (u16*)(ws + NT * 2);
  u16* Qh = (u16*)(ws + NT * 2 + NW * 2);
  u16* Kh = Qh + NT;
  u16* Vh = Kh + NT;
  u16* Obf = Vh + NT;

  const dim3 blk(256);
  const dim3 gact((unsigned)(NT / 1024));
  const dim3 gw((unsigned)(NW / 1024));
  const dim3 ggemm(M / BM, D / BN);
  const dim3 gattn(Bv * 16 * (S / QBLK));  // 512

  conv_f32_bf16<<<gact, blk, 0, stream>>>(q, Xbf);
  conv_f32_bf16<<<gw, blk, 0, stream>>>(wq_w, Wbf);
  gemm_bt<<<ggemm, blk, 0, stream>>>(Xbf, Wbf, wq_b, Qh, M, D, D, 0);
  conv_f32_bf16<<<gact, blk, 0, stream>>>(k, Xbf);
  conv_f32_bf16<<<gw, blk, 0, stream>>>(wk_w, Wbf);
  gemm_bt<<<ggemm, blk, 0, stream>>>(Xbf, Wbf, wk_b, Kh, M, D, D, 0);
  conv_f32_bf16<<<gact, blk, 0, stream>>>(v, Xbf);
  conv_f32_bf16<<<gw, blk, 0, stream>>>(wv_w, Wbf);
  gemm_bt<<<ggemm, blk, 0, stream>>>(Xbf, Wbf, wv_b, Vh, M, D, D, 0);
  flash_attn<<<gattn, blk, 0, stream>>>(Qh, Kh, Vh, Obf);
  conv_f32_bf16<<<gw, blk, 0, stream>>>(dw, Wbf);
  gemm_bt<<<ggemm, blk, 0, stream>>>(Obf, Wbf, db, out, M, D, D, 1);
}

// Round 5
// 372.232 us; speedup vs baseline: 2.0452x; 1.0580x over previous
//
#include <hip/hip_runtime.h>
#include <hip/hip_bf16.h>

// GPT3 attention block, B=2 S=2048 D=2048 H=16 Dh=128.
// Ring-pipelined (counted-vmcnt) bf16 MFMA GEMMs + swapped-QK^T 32x32
// flash attention with in-register softmax.

typedef __bf16 bf16x8 __attribute__((ext_vector_type(8)));
typedef float f32x4 __attribute__((ext_vector_type(4)));
typedef float f32x16 __attribute__((ext_vector_type(16)));
typedef unsigned short u16;
typedef unsigned int u32;

#define DEV static __device__ __forceinline__

DEV void gload_lds16(const void* g, void* l) {
  __builtin_amdgcn_global_load_lds(
      (const __attribute__((address_space(1))) void*)g,
      (__attribute__((address_space(3))) void*)l, 16, 0, 0);
}

DEV f32x4 mfma16(bf16x8 a, bf16x8 b, f32x4 c) {
  return __builtin_amdgcn_mfma_f32_16x16x32_bf16(a, b, c, 0, 0, 0);
}

DEV f32x16 mfma32(bf16x8 a, bf16x8 b, f32x16 c) {
  return __builtin_amdgcn_mfma_f32_32x32x16_bf16(a, b, c, 0, 0, 0);
}

DEV u16 f2bf(float x) {
  return __builtin_bit_cast(u16, __float2bfloat16(x));
}

DEV u32 pack2(float lo, float hi_) {
  return (u32)f2bf(lo) | ((u32)f2bf(hi_) << 16);
}

// ---------------- fp32 -> bf16 conversion (vectorized) ----------------
__global__ void __launch_bounds__(256) conv_f32_bf16(
    const float* __restrict__ in, u16* __restrict__ out) {
  const size_t i = ((size_t)blockIdx.x * 256 + threadIdx.x) * 4;
  const float4 v = *reinterpret_cast<const float4*>(in + i);
  ushort4 o;
  o.x = f2bf(v.x); o.y = f2bf(v.y); o.z = f2bf(v.z); o.w = f2bf(v.w);
  *reinterpret_cast<ushort4*>(out + i) = o;
}

// ---------------- ring-pipelined GEMM: C = A @ B^T + bias -------------
// 128x128 tile, BK=32, K=2048 fixed. 4-deep LDS ring, counted vmcnt:
// iter t stages tile t+3 (4 gload_lds/thread), computes tile t, then
// s_waitcnt vmcnt(8) + raw s_barrier  =>  invariant: tile t+1 landed.
// Overwrite of buf[(t+3)&3] is safe: last read 2 barriers earlier.
// LDS layout: pair-row (128B) 16B-chunk XOR swizzle  slot' = slot ^ (rp&7)
// applied on the pre-swizzled gload SOURCE; ds_read applies same XOR.
#define GBM 128
#define GBN 128
#define GBK 32
#define GK 2048
#define GNT 64  // GK / GBK

__global__ void __launch_bounds__(256, 2) gemm_ring(
    const u16* __restrict__ A, const u16* __restrict__ Bw,
    const float* __restrict__ bias, void* __restrict__ Cout,
    const int Mblocks, const int N, const int out_f32) {
  __shared__ u16 As[4][GBM * GBK];  // 32 KB
  __shared__ u16 Bs[4][GBN * GBK];  // 32 KB

  const int tid = threadIdx.x;
  const int lane = tid & 63;
  const int w = tid >> 6;
  const int wr = w >> 1, wc = w & 1;
  const int g = lane >> 4;
  const int r16 = lane & 15;

  // XCD-aware swizzle (grid divisible by 8); bx fast => same-column-panel
  // blocks land on one XCD's L2.
  const int cpx = gridDim.x >> 3;
  int bid = blockIdx.x;
  bid = (bid & 7) * cpx + (bid >> 3);
  const int m0 = (bid % Mblocks) * GBM;
  const int n0 = (bid / Mblocks) * GBN;

  // staging source offsets (inverse-swizzled global source, linear LDS dest)
  int offA[2], offB[2], dst[2];
#pragma unroll
  for (int rr = 0; rr < 2; ++rr) {
    const int G = rr * 64 + lane;          // wave-local 16B-chunk slot
    const int rp = w * 16 + (G >> 3);      // row-pair 0..63
    const int s = (G & 7) ^ (rp & 7);      // source slot in 128B row-pair
    const int row = rp * 2 + (s >> 2);
    const int ch = s & 3;
    offA[rr] = (m0 + row) * GK + ch * 8;
    offB[rr] = (n0 + row) * GK + ch * 8;
    dst[rr] = w * 1024 + rr * 512;         // wave-uniform LDS base (elems)
  }

  const f32x4 zero = {0.f, 0.f, 0.f, 0.f};
  f32x4 acc[4][4];
#pragma unroll
  for (int i = 0; i < 4; ++i)
#pragma unroll
    for (int j = 0; j < 4; ++j) acc[i][j] = zero;

  auto stage = [&](int t) {
    const int kk = t * GBK;
    const int bi = t & 3;
    gload_lds16(A + offA[0] + kk, &As[bi][dst[0]]);
    gload_lds16(A + offA[1] + kk, &As[bi][dst[1]]);
    gload_lds16(Bw + offB[0] + kk, &Bs[bi][dst[0]]);
    gload_lds16(Bw + offB[1] + kk, &Bs[bi][dst[1]]);
  };

  auto compute = [&](int t) {
    const int bi = t & 3;
    bf16x8 af[4], bf[4];
#pragma unroll
    for (int i = 0; i < 4; ++i) {
      const int row = wr * 64 + i * 16 + r16;
      const int rp = row >> 1;
      const int sl = (((row & 1) << 2) | g) ^ (rp & 7);
      af[i] = *reinterpret_cast<const bf16x8*>(&As[bi][rp * 64 + sl * 8]);
      const int rowb = wc * 64 + i * 16 + r16;
      const int rpb = rowb >> 1;
      const int slb = (((rowb & 1) << 2) | g) ^ (rpb & 7);
      bf[i] = *reinterpret_cast<const bf16x8*>(&Bs[bi][rpb * 64 + slb * 8]);
    }
    __builtin_amdgcn_s_setprio(1);
#pragma unroll
    for (int i = 0; i < 4; ++i)
#pragma unroll
      for (int j = 0; j < 4; ++j)
        acc[i][j] = mfma16(af[i], bf[j], acc[i][j]);
    __builtin_amdgcn_s_setprio(0);
  };

  // prologue: 3 tiles in flight; wait tile 0 (12 outstanding -> 8)
  stage(0); stage(1); stage(2);
  asm volatile("s_waitcnt vmcnt(8)" ::: "memory");
  __builtin_amdgcn_s_barrier();
  __builtin_amdgcn_sched_barrier(0);

  for (int t = 0; t <= GNT - 4; ++t) {
    stage(t + 3);
    compute(t);
    asm volatile("s_waitcnt vmcnt(8)" ::: "memory");  // tile t+1 landed
    __builtin_amdgcn_s_barrier();
    __builtin_amdgcn_sched_barrier(0);
  }
  compute(GNT - 3);
  asm volatile("s_waitcnt vmcnt(4)" ::: "memory");    // tile GNT-2 landed
  __builtin_amdgcn_s_barrier();
  __builtin_amdgcn_sched_barrier(0);
  compute(GNT - 2);
  asm volatile("s_waitcnt vmcnt(0)" ::: "memory");    // tile GNT-1 landed
  __builtin_amdgcn_s_barrier();
  __builtin_amdgcn_sched_barrier(0);
  compute(GNT - 1);

  // epilogue: C/D layout col=lane&15, row=(lane>>4)*4+reg
  const int cbase = n0 + wc * 64 + r16;
  const int rbase = m0 + wr * 64 + g * 4;
#pragma unroll
  for (int i = 0; i < 4; ++i) {
#pragma unroll
    for (int j = 0; j < 4; ++j) {
      const int c = cbase + j * 16;
      const float bv = bias[c];
#pragma unroll
      for (int r = 0; r < 4; ++r) {
        const float v = acc[i][j][r] + bv;
        const size_t idx = (size_t)(rbase + i * 16 + r) * N + c;
        if (out_f32) ((float*)Cout)[idx] = v;
        else ((u16*)Cout)[idx] = f2bf(v);
      }
    }
  }
}

// ---------------- causal flash attention (swapped QK^T, 32x32) --------
#define SEQ 2048
#define DMODEL 2048
#define DH 128
#define QBLK 128
#define KBLK 64
#define C1 0.12751744f   // (1/sqrt(128)) * log2(e)
#define THR_RAW 62.73f   // defer-max threshold: 8 / C1

__global__ void __launch_bounds__(256, 2) flash_attn(
    const u16* __restrict__ Qh, const u16* __restrict__ Kh,
    const u16* __restrict__ Vh, u16* __restrict__ O) {
  __shared__ u16 Ks[KBLK * DH];  // 16 KB
  __shared__ u16 Vt[DH * KBLK];  // 16 KB

  const int tid = threadIdx.x;
  const int lane = tid & 63;
  const int w = tid >> 6;
  const int hi = lane >> 5;
  const int l31 = lane & 31;

  const int bh = blockIdx.x >> 4;
  const int qt = (blockIdx.x & 15) ^ (bh & 15);
  const int h = bh & 15;
  const int b = bh >> 4;
  const int q0 = qt * QBLK;
  const size_t rowbase = (size_t)b * SEQ;
  const int hoff = h * DH;
  const int qw = q0 + w * 32;
  const int qlane = qw + l31;

  bf16x8 aq[8];
  {
    const u16* qp = &Qh[(rowbase + qlane) * DMODEL + hoff + hi * 8];
#pragma unroll
    for (int c = 0; c < 8; ++c)
      aq[c] = *reinterpret_cast<const bf16x8*>(qp + c * 16);
  }

  f32x16 oacc[4];
#pragma unroll
  for (int dt = 0; dt < 4; ++dt)
#pragma unroll
    for (int r = 0; r < 16; ++r) oacc[dt][r] = 0.f;
  float mrow = -1e30f, lrow = 0.f;

  const int krl = w * 16 + (lane >> 4);
  const int kg4 = w * 4 + (lane >> 4);
  const int du = lane & 15;

  const int nkt = 2 * qt + 2;
  const int ktd = qw >> 6;

  uint4 vv[4];
#pragma unroll
  for (int r = 0; r < 4; ++r)
    vv[r] = *reinterpret_cast<const uint4*>(
        &Vh[(rowbase + kg4 * 4 + r) * DMODEL + hoff + du * 8]);

  for (int kt = 0; kt < nkt; ++kt) {
    const int k0 = kt * KBLK;
    __syncthreads();

#pragma unroll
    for (int i = 0; i < 4; ++i) {
      const int r = krl + i * 4;
      const int cg = (lane & 15) ^ (r & 15);
      gload_lds16(&Kh[(rowbase + k0 + r) * DMODEL + hoff + cg * 8],
                  &Ks[(w * 16 + i * 4) * DH]);
    }

#pragma unroll
    for (int j = 0; j < 8; ++j) {
      const int d = du * 8 + j;
      ushort4 pk4;
      pk4.x = ((const u16*)&vv[0])[j];
      pk4.y = ((const u16*)&vv[1])[j];
      pk4.z = ((const u16*)&vv[2])[j];
      pk4.w = ((const u16*)&vv[3])[j];
      const int slot = (((kg4 >> 1) ^ ((d >> 2) & 7)) * 8) + (kg4 & 1) * 4;
      *reinterpret_cast<ushort4*>(&Vt[d * KBLK + slot]) = pk4;
    }

    __syncthreads();

    if (kt + 1 < nkt) {
#pragma unroll
      for (int r = 0; r < 4; ++r)
        vv[r] = *reinterpret_cast<const uint4*>(
            &Vh[(rowbase + k0 + KBLK + kg4 * 4 + r) * DMODEL + hoff + du * 8]);
    }

    if (kt > ktd) continue;

    const bool diag = (kt == ktd);
    const bool act1 = (kt < ktd) || (w & 1);
    const bool m0q = diag && !(w & 1);
    const bool m1q = diag && (w & 1);

    float p[2][16];
    {
      f32x16 s;
#pragma unroll
      for (int r = 0; r < 16; ++r) s[r] = 0.f;
      __builtin_amdgcn_s_setprio(1);
#pragma unroll
      for (int c = 0; c < 8; ++c) {
        const int row = l31;
        const bf16x8 kf = *reinterpret_cast<const bf16x8*>(
            &Ks[row * DH + (((c * 2 + hi) ^ (row & 15)) * 8)]);
        s = mfma32(kf, aq[c], s);
      }
      __builtin_amdgcn_s_setprio(0);
#pragma unroll
      for (int r = 0; r < 16; ++r) {
        const int krow = (r & 3) + 8 * (r >> 2) + 4 * hi;
        p[0][r] = (m0q && (k0 + krow > qlane)) ? -1e9f : s[r];
      }
    }
    if (act1) {
      f32x16 s;
#pragma unroll
      for (int r = 0; r < 16; ++r) s[r] = 0.f;
      __builtin_amdgcn_s_setprio(1);
#pragma unroll
      for (int c = 0; c < 8; ++c) {
        const int row = 32 + l31;
        const bf16x8 kf = *reinterpret_cast<const bf16x8*>(
            &Ks[row * DH + (((c * 2 + hi) ^ (row & 15)) * 8)]);
        s = mfma32(kf, aq[c], s);
      }
      __builtin_amdgcn_s_setprio(0);
#pragma unroll
      for (int r = 0; r < 16; ++r) {
        const int krow = (r & 3) + 8 * (r >> 2) + 4 * hi;
        p[1][r] = (m1q && (k0 + 32 + krow > qlane)) ? -1e9f : s[r];
      }
    } else {
#pragma unroll
      for (int r = 0; r < 16; ++r) p[1][r] = -1e9f;
    }

    float mx = fmaxf(p[0][0], p[0][1]);
#pragma unroll
    for (int r = 2; r < 16; ++r) mx = fmaxf(mx, p[0][r]);
#pragma unroll
    for (int r = 0; r < 16; ++r) mx = fmaxf(mx, p[1][r]);
    mx = fmaxf(mx, __shfl_xor(mx, 32));

    const bool need = (mx > mrow + THR_RAW);
    if (__any((int)need)) {
      const float mn = fmaxf(mrow, mx);
      const float al = exp2f((mrow - mn) * C1);
      mrow = mn;
      lrow *= al;
#pragma unroll
      for (int r = 0; r < 16; ++r) {
        const float ar = __shfl(al, (r & 3) + 8 * (r >> 2) + 4 * hi);
#pragma unroll
        for (int dt = 0; dt < 4; ++dt) oacc[dt][r] *= ar;
      }
    }

    float sum = 0.f;
#pragma unroll
    for (int t = 0; t < 2; ++t)
#pragma unroll
      for (int r = 0; r < 16; ++r) {
        p[t][r] = exp2f((p[t][r] - mrow) * C1);
        sum += p[t][r];
      }
    sum += __shfl_xor(sum, 32);
    lrow += sum;

    u32 pk[2][8];
#pragma unroll
    for (int t = 0; t < 2; ++t)
#pragma unroll
      for (int m = 0; m < 8; ++m)
        pk[t][m] = pack2(p[t][2 * m], p[t][2 * m + 1]);

    __builtin_amdgcn_s_setprio(1);
#pragma unroll
    for (int ks = 0; ks < 4; ++ks) {
      if (ks >= 2 && !act1) break;
      const int t = ks >> 1;
      const int bs = (ks & 1) * 4;
      const u32 s0 = __shfl_xor(pk[t][bs + 0], 32);
      const u32 s1 = __shfl_xor(pk[t][bs + 1], 32);
      const u32 s2 = __shfl_xor(pk[t][bs + 2], 32);
      const u32 s3 = __shfl_xor(pk[t][bs + 3], 32);
      union { u32 u[4]; bf16x8 v; } pa;
      pa.u[0] = hi ? s2 : pk[t][bs + 0];
      pa.u[1] = hi ? s3 : pk[t][bs + 1];
      pa.u[2] = hi ? pk[t][bs + 2] : s0;
      pa.u[3] = hi ? pk[t][bs + 3] : s1;
#pragma unroll
      for (int dt = 0; dt < 4; ++dt) {
        const int d = dt * 32 + l31;
        const bf16x8 vf = *reinterpret_cast<const bf16x8*>(
            &Vt[d * KBLK + (((ks * 2 + hi) ^ ((d >> 2) & 7)) * 8)]);
        oacc[dt] = mfma32(pa.v, vf, oacc[dt]);
      }
    }
    __builtin_amdgcn_s_setprio(0);
  }

  const float li = __builtin_amdgcn_rcpf(lrow);
#pragma unroll
  for (int r = 0; r < 16; ++r) {
    const int rowq = (r & 3) + 8 * (r >> 2) + 4 * hi;
    const float lr = __shfl(li, rowq);
    u16* op = &O[(rowbase + qw + rowq) * DMODEL + hoff + l31];
#pragma unroll
    for (int dt = 0; dt < 4; ++dt) op[dt * 32] = f2bf(oacc[dt][r] * lr);
  }
}

// ---------------- launcher --------------------------------------------
extern "C" void kernel_launch(void* const* d_in, const int* in_sizes, int n_in,
                              void* d_out, int out_size, void* d_ws,
                              size_t ws_size, hipStream_t stream) {
  const int Bv = 2, S = 2048, D = 2048;
  const int M = Bv * S;
  const size_t NT = (size_t)M * D;
  const size_t NW = (size_t)D * D;

  const float* q = (const float*)d_in[0];
  const float* k = (const float*)d_in[1];
  const float* v = (const float*)d_in[2];
  const float* wq_w = (const float*)d_in[4];
  const float* wq_b = (const float*)d_in[5];
  const float* wk_w = (const float*)d_in[6];
  const float* wk_b = (const float*)d_in[7];
  const float* wv_w = (const float*)d_in[8];
  const float* wv_b = (const float*)d_in[9];
  const float* dw = (const float*)d_in[10];
  const float* db = (const float*)d_in[11];
  float* out = (float*)d_out;

  char* ws = (char*)d_ws;
  u16* Xbf = (u16*)ws;
  u16* Wbf = (u16*)(ws + NT * 2);
  u16* Qh = (u16*)(ws + NT * 2 + NW * 2);
  u16* Kh = Qh + NT;
  u16* Vh = Kh + NT;
  u16* Obf = Vh + NT;

  const dim3 blk(256);
  const dim3 gact((unsigned)(NT / 1024));
  const dim3 gw((unsigned)(NW / 1024));
  const dim3 ggemm((M / GBM) * (D / GBN));  // 512, 1D grid (XCD swizzle)
  const dim3 gattn(Bv * 16 * (S / QBLK));   // 512

  conv_f32_bf16<<<gact, blk, 0, stream>>>(q, Xbf);
  conv_f32_bf16<<<gw, blk, 0, stream>>>(wq_w, Wbf);
  gemm_ring<<<ggemm, blk, 0, stream>>>(Xbf, Wbf, wq_b, Qh, M / GBM, D, 0);
  conv_f32_bf16<<<gact, blk, 0, stream>>>(k, Xbf);
  conv_f32_bf16<<<gw, blk, 0, stream>>>(wk_w, Wbf);
  gemm_ring<<<ggemm, blk, 0, stream>>>(Xbf, Wbf, wk_b, Kh, M / GBM, D, 0);
  conv_f32_bf16<<<gact, blk, 0, stream>>>(v, Xbf);
  conv_f32_bf16<<<gw, blk, 0, stream>>>(wv_w, Wbf);
  gemm_ring<<<ggemm, blk, 0, stream>>>(Xbf, Wbf, wv_b, Vh, M / GBM, D, 0);
  flash_attn<<<gattn, blk, 0, stream>>>(Qh, Kh, Vh, Obf);
  conv_f32_bf16<<<gw, blk, 0, stream>>>(dw, Wbf);
  gemm_ring<<<ggemm, blk, 0, stream>>>(Obf, Wbf, db, out, M / GBM, D, 1);
}

// Round 6
// 342.789 us; speedup vs baseline: 2.2209x; 1.0859x over previous
//
#include <hip/hip_runtime.h>
#include <hip/hip_bf16.h>

// GPT3 attention block, B=2 S=2048 D=2048 H=16 Dh=128.
// Ring-pipelined (counted-vmcnt) bf16 MFMA GEMMs + swapped-QK^T 32x32
// flash attention with in-register softmax and complement-paired blocks.

typedef __bf16 bf16x8 __attribute__((ext_vector_type(8)));
typedef float f32x4 __attribute__((ext_vector_type(4)));
typedef float f32x16 __attribute__((ext_vector_type(16)));
typedef unsigned short u16;
typedef unsigned int u32;

#define DEV static __device__ __forceinline__

DEV void gload_lds16(const void* g, void* l) {
  __builtin_amdgcn_global_load_lds(
      (const __attribute__((address_space(1))) void*)g,
      (__attribute__((address_space(3))) void*)l, 16, 0, 0);
}

DEV f32x4 mfma16(bf16x8 a, bf16x8 b, f32x4 c) {
  return __builtin_amdgcn_mfma_f32_16x16x32_bf16(a, b, c, 0, 0, 0);
}

DEV f32x16 mfma32(bf16x8 a, bf16x8 b, f32x16 c) {
  return __builtin_amdgcn_mfma_f32_32x32x16_bf16(a, b, c, 0, 0, 0);
}

DEV u16 f2bf(float x) {
  return __builtin_bit_cast(u16, __float2bfloat16(x));
}

DEV u32 pack2(float lo, float hi_) {
  return (u32)f2bf(lo) | ((u32)f2bf(hi_) << 16);
}

// ---------------- fp32 -> bf16 conversion ----------------------------
__global__ void __launch_bounds__(256) conv_f32_bf16(
    const float* __restrict__ in, u16* __restrict__ out) {
  const size_t i = ((size_t)blockIdx.x * 256 + threadIdx.x) * 4;
  const float4 v = *reinterpret_cast<const float4*>(in + i);
  ushort4 o;
  o.x = f2bf(v.x); o.y = f2bf(v.y); o.z = f2bf(v.z); o.w = f2bf(v.w);
  *reinterpret_cast<ushort4*>(out + i) = o;
}

// fused: 3 activations (n = nact) + 4 weights (n = nw), job = blockIdx.y
__global__ void __launch_bounds__(256) conv_all(
    const float* __restrict__ s0, const float* __restrict__ s1,
    const float* __restrict__ s2, const float* __restrict__ s3,
    const float* __restrict__ s4, const float* __restrict__ s5,
    const float* __restrict__ s6,
    u16* __restrict__ d0, u16* __restrict__ d1, u16* __restrict__ d2,
    u16* __restrict__ d3, u16* __restrict__ d4, u16* __restrict__ d5,
    u16* __restrict__ d6, const size_t nact, const size_t nw) {
  const int j = blockIdx.y;
  const size_t i = ((size_t)blockIdx.x * 256 + threadIdx.x) * 4;
  const float* s; u16* d; size_t n;
  switch (j) {
    case 0: s = s0; d = d0; n = nact; break;
    case 1: s = s1; d = d1; n = nact; break;
    case 2: s = s2; d = d2; n = nact; break;
    case 3: s = s3; d = d3; n = nw; break;
    case 4: s = s4; d = d4; n = nw; break;
    case 5: s = s5; d = d5; n = nw; break;
    default: s = s6; d = d6; n = nw; break;
  }
  if (i >= n) return;
  const float4 v = *reinterpret_cast<const float4*>(s + i);
  ushort4 o;
  o.x = f2bf(v.x); o.y = f2bf(v.y); o.z = f2bf(v.z); o.w = f2bf(v.w);
  *reinterpret_cast<ushort4*>(d + i) = o;
}

// ---------------- ring-pipelined GEMM core: C = A @ B^T + bias --------
// 128x128 tile, BK=32, K=2048. 4-deep LDS ring, counted vmcnt(8):
// iter t stages tile t+3, computes tile t; one barrier per K-step; loads
// never drained to 0 in the main loop. Pair-row 16B-chunk XOR swizzle on
// the pre-swizzled gload SOURCE; ds_read applies the same XOR.
#define GBM 128
#define GBN 128
#define GBK 32
#define GK 2048
#define GNT 64  // GK / GBK

DEV void gemm_core(const u16* __restrict__ A, const u16* __restrict__ Bw,
                   const float* __restrict__ bias, void* __restrict__ Cout,
                   const int m0, const int n0, const int N, const int out_f32,
                   u16* As, u16* Bs) {
  const int tid = threadIdx.x;
  const int lane = tid & 63;
  const int w = tid >> 6;
  const int wr = w >> 1, wc = w & 1;
  const int g = lane >> 4;
  const int r16 = lane & 15;

  int offA[2], offB[2], dst2[2];
#pragma unroll
  for (int rr = 0; rr < 2; ++rr) {
    const int G = rr * 64 + lane;          // wave-local 16B-chunk slot
    const int rp = w * 16 + (G >> 3);      // row-pair 0..63
    const int s = (G & 7) ^ (rp & 7);      // source slot in 128B row-pair
    const int row = rp * 2 + (s >> 2);
    const int ch = s & 3;
    offA[rr] = (m0 + row) * GK + ch * 8;
    offB[rr] = (n0 + row) * GK + ch * 8;
    dst2[rr] = w * 1024 + rr * 512;        // wave-uniform LDS base (elems)
  }

  f32x4 acc[4][4];
#pragma unroll
  for (int i = 0; i < 4; ++i)
#pragma unroll
    for (int j = 0; j < 4; ++j) acc[i][j] = {0.f, 0.f, 0.f, 0.f};

  auto stage = [&](int t) {
    const int kk = t * GBK;
    u16* as = As + (t & 3) * 4096;
    u16* bs = Bs + (t & 3) * 4096;
    gload_lds16(A + offA[0] + kk, as + dst2[0]);
    gload_lds16(A + offA[1] + kk, as + dst2[1]);
    gload_lds16(Bw + offB[0] + kk, bs + dst2[0]);
    gload_lds16(Bw + offB[1] + kk, bs + dst2[1]);
  };

  auto compute = [&](int t) {
    const u16* as = As + (t & 3) * 4096;
    const u16* bs = Bs + (t & 3) * 4096;
    bf16x8 af[4], bf[4];
#pragma unroll
    for (int i = 0; i < 4; ++i) {
      const int row = wr * 64 + i * 16 + r16;
      const int rp = row >> 1;
      const int sl = (((row & 1) << 2) | g) ^ (rp & 7);
      af[i] = *reinterpret_cast<const bf16x8*>(as + rp * 64 + sl * 8);
      const int rowb = wc * 64 + i * 16 + r16;
      const int rpb = rowb >> 1;
      const int slb = (((rowb & 1) << 2) | g) ^ (rpb & 7);
      bf[i] = *reinterpret_cast<const bf16x8*>(bs + rpb * 64 + slb * 8);
    }
#pragma unroll
    for (int i = 0; i < 4; ++i)
#pragma unroll
      for (int j = 0; j < 4; ++j)
        acc[i][j] = mfma16(af[i], bf[j], acc[i][j]);
  };

  // prologue: 3 tiles in flight; wait tile 0 (12 outstanding -> 8)
  stage(0); stage(1); stage(2);
  asm volatile("s_waitcnt vmcnt(8)" ::: "memory");
  __builtin_amdgcn_s_barrier();

  for (int t = 0; t <= GNT - 4; ++t) {
    stage(t + 3);
    compute(t);
    asm volatile("s_waitcnt vmcnt(8) lgkmcnt(0)" ::: "memory");
    __builtin_amdgcn_s_barrier();
  }
  compute(GNT - 3);
  asm volatile("s_waitcnt vmcnt(4) lgkmcnt(0)" ::: "memory");
  __builtin_amdgcn_s_barrier();
  compute(GNT - 2);
  asm volatile("s_waitcnt vmcnt(0) lgkmcnt(0)" ::: "memory");
  __builtin_amdgcn_s_barrier();
  compute(GNT - 1);

  // epilogue: C/D layout col=lane&15, row=(lane>>4)*4+reg
  const int cbase = n0 + wc * 64 + r16;
  const int rbase = m0 + wr * 64 + g * 4;
#pragma unroll
  for (int i = 0; i < 4; ++i) {
#pragma unroll
    for (int j = 0; j < 4; ++j) {
      const int c = cbase + j * 16;
      const float bv = bias[c];
#pragma unroll
      for (int r = 0; r < 4; ++r) {
        const float v = acc[i][j][r] + bv;
        const size_t idx = (size_t)(rbase + i * 16 + r) * N + c;
        if (out_f32) ((float*)Cout)[idx] = v;
        else ((u16*)Cout)[idx] = f2bf(v);
      }
    }
  }
}

__global__ void __launch_bounds__(256, 2) gemm_ring(
    const u16* __restrict__ A, const u16* __restrict__ Bw,
    const float* __restrict__ bias, void* __restrict__ Cout,
    const int Mblocks, const int N, const int out_f32) {
  __shared__ u16 As[4 * GBM * GBK];
  __shared__ u16 Bs[4 * GBN * GBK];
  const int cpx = gridDim.x >> 3;
  int bid = blockIdx.x;
  bid = (bid & 7) * cpx + (bid >> 3);
  const int m0 = (bid % Mblocks) * GBM;
  const int n0 = (bid / Mblocks) * GBN;
  gemm_core(A, Bw, bias, Cout, m0, n0, N, out_f32, As, Bs);
}

// fused Q/K/V projections: grid 1536 = 3 x 512
__global__ void __launch_bounds__(256, 2) gemm_qkv(
    const u16* __restrict__ A0, const u16* __restrict__ A1,
    const u16* __restrict__ A2, const u16* __restrict__ W0,
    const u16* __restrict__ W1, const u16* __restrict__ W2,
    const float* __restrict__ b0, const float* __restrict__ b1,
    const float* __restrict__ b2, u16* __restrict__ C0,
    u16* __restrict__ C1, u16* __restrict__ C2) {
  __shared__ u16 As[4 * GBM * GBK];
  __shared__ u16 Bs[4 * GBN * GBK];
  const int which = blockIdx.x >> 9;
  const int inner = blockIdx.x & 511;
  const int bid = (inner & 7) * 64 + (inner >> 3);  // XCD-aware swizzle
  const int m0 = (bid & 31) * GBM;   // Mblocks = 32
  const int n0 = (bid >> 5) * GBN;
  const u16* A = which == 0 ? A0 : which == 1 ? A1 : A2;
  const u16* W = which == 0 ? W0 : which == 1 ? W1 : W2;
  const float* bb = which == 0 ? b0 : which == 1 ? b1 : b2;
  u16* C = which == 0 ? C0 : which == 1 ? C1 : C2;
  gemm_core(A, W, bb, C, m0, n0, 2048, 0, As, Bs);
}

// ---------------- causal flash attention (swapped QK^T, 32x32) --------
#define SEQ 2048
#define DMODEL 2048
#define DH 128
#define QBLK 128
#define KBLK 64
#define C1 0.12751744f   // (1/sqrt(128)) * log2(e)
#define THR_RAW 62.73f   // defer-max threshold: 8 / C1

__global__ void __launch_bounds__(256, 2) flash_attn(
    const u16* __restrict__ Qh, const u16* __restrict__ Kh,
    const u16* __restrict__ Vh, u16* __restrict__ O) {
  __shared__ u16 Ks[KBLK * DH];  // 16 KB
  __shared__ u16 Vt[DH * KBLK];  // 16 KB

  const int tid = threadIdx.x;
  const int lane = tid & 63;
  const int w = tid >> 6;
  const int hi = lane >> 5;
  const int l31 = lane & 31;

  // complement-paired qt: co-resident blocks (c, c+256) differ only in the
  // b-bit; mapping b=1 to 15-qt makes each CU's pair sum to a uniform 36
  // k-tiles (kills the makespan imbalance seen in r5).
  const int cc = blockIdx.x;
  const int low = cc & 15;
  const int bh = (cc >> 4) & 31;
  const int h = bh & 15;
  const int b = bh >> 4;
  const int g0 = low ^ h;
  const int qt = b ? (15 - g0) : g0;
  const int q0 = qt * QBLK;
  const size_t rowbase = (size_t)b * SEQ;
  const int hoff = h * DH;
  const int qw = q0 + w * 32;
  const int qlane = qw + l31;

  bf16x8 aq[8];
  {
    const u16* qp = &Qh[(rowbase + qlane) * DMODEL + hoff + hi * 8];
#pragma unroll
    for (int c = 0; c < 8; ++c)
      aq[c] = *reinterpret_cast<const bf16x8*>(qp + c * 16);
  }

  f32x16 oacc[4];
#pragma unroll
  for (int dt = 0; dt < 4; ++dt)
#pragma unroll
    for (int r = 0; r < 16; ++r) oacc[dt][r] = 0.f;
  float mrow = -1e30f, lrow = 0.f;

  const int krl = w * 16 + (lane >> 4);
  const int kg4 = w * 4 + (lane >> 4);
  const int du = lane & 15;

  const int nkt = 2 * qt + 2;
  const int ktd = qw >> 6;

  uint4 vv[4];
#pragma unroll
  for (int r = 0; r < 4; ++r)
    vv[r] = *reinterpret_cast<const uint4*>(
        &Vh[(rowbase + kg4 * 4 + r) * DMODEL + hoff + du * 8]);

  for (int kt = 0; kt < nkt; ++kt) {
    const int k0 = kt * KBLK;
    __syncthreads();

#pragma unroll
    for (int i = 0; i < 4; ++i) {
      const int r = krl + i * 4;
      const int cg = (lane & 15) ^ (r & 15);
      gload_lds16(&Kh[(rowbase + k0 + r) * DMODEL + hoff + cg * 8],
                  &Ks[(w * 16 + i * 4) * DH]);
    }

#pragma unroll
    for (int j = 0; j < 8; ++j) {
      const int d = du * 8 + j;
      ushort4 pk4;
      pk4.x = ((const u16*)&vv[0])[j];
      pk4.y = ((const u16*)&vv[1])[j];
      pk4.z = ((const u16*)&vv[2])[j];
      pk4.w = ((const u16*)&vv[3])[j];
      const int slot = (((kg4 >> 1) ^ ((d >> 2) & 7)) * 8) + (kg4 & 1) * 4;
      *reinterpret_cast<ushort4*>(&Vt[d * KBLK + slot]) = pk4;
    }

    __syncthreads();

    if (kt + 1 < nkt) {
#pragma unroll
      for (int r = 0; r < 4; ++r)
        vv[r] = *reinterpret_cast<const uint4*>(
            &Vh[(rowbase + k0 + KBLK + kg4 * 4 + r) * DMODEL + hoff + du * 8]);
    }

    if (kt > ktd) continue;

    const bool diag = (kt == ktd);
    const bool act1 = (kt < ktd) || (w & 1);
    const bool m0q = diag && !(w & 1);
    const bool m1q = diag && (w & 1);

    float p[2][16];
    {
      f32x16 s;
#pragma unroll
      for (int r = 0; r < 16; ++r) s[r] = 0.f;
      __builtin_amdgcn_s_setprio(1);
#pragma unroll
      for (int c = 0; c < 8; ++c) {
        const int row = l31;
        const bf16x8 kf = *reinterpret_cast<const bf16x8*>(
            &Ks[row * DH + (((c * 2 + hi) ^ (row & 15)) * 8)]);
        s = mfma32(kf, aq[c], s);
      }
      __builtin_amdgcn_s_setprio(0);
#pragma unroll
      for (int r = 0; r < 16; ++r) {
        const int krow = (r & 3) + 8 * (r >> 2) + 4 * hi;
        p[0][r] = (m0q && (k0 + krow > qlane)) ? -1e9f : s[r];
      }
    }
    if (act1) {
      f32x16 s;
#pragma unroll
      for (int r = 0; r < 16; ++r) s[r] = 0.f;
      __builtin_amdgcn_s_setprio(1);
#pragma unroll
      for (int c = 0; c < 8; ++c) {
        const int row = 32 + l31;
        const bf16x8 kf = *reinterpret_cast<const bf16x8*>(
            &Ks[row * DH + (((c * 2 + hi) ^ (row & 15)) * 8)]);
        s = mfma32(kf, aq[c], s);
      }
      __builtin_amdgcn_s_setprio(0);
#pragma unroll
      for (int r = 0; r < 16; ++r) {
        const int krow = (r & 3) + 8 * (r >> 2) + 4 * hi;
        p[1][r] = (m1q && (k0 + 32 + krow > qlane)) ? -1e9f : s[r];
      }
    } else {
#pragma unroll
      for (int r = 0; r < 16; ++r) p[1][r] = -1e9f;
    }

    float mx = fmaxf(p[0][0], p[0][1]);
#pragma unroll
    for (int r = 2; r < 16; ++r) mx = fmaxf(mx, p[0][r]);
#pragma unroll
    for (int r = 0; r < 16; ++r) mx = fmaxf(mx, p[1][r]);
    mx = fmaxf(mx, __shfl_xor(mx, 32));

    const bool need = (mx > mrow + THR_RAW);
    if (__any((int)need)) {
      const float mn = fmaxf(mrow, mx);
      const float al = exp2f((mrow - mn) * C1);
      mrow = mn;
      lrow *= al;
#pragma unroll
      for (int r = 0; r < 16; ++r) {
        const float ar = __shfl(al, (r & 3) + 8 * (r >> 2) + 4 * hi);
#pragma unroll
        for (int dt = 0; dt < 4; ++dt) oacc[dt][r] *= ar;
      }
    }

    float sum = 0.f;
#pragma unroll
    for (int t = 0; t < 2; ++t)
#pragma unroll
      for (int r = 0; r < 16; ++r) {
        p[t][r] = exp2f((p[t][r] - mrow) * C1);
        sum += p[t][r];
      }
    sum += __shfl_xor(sum, 32);
    lrow += sum;

    u32 pk[2][8];
#pragma unroll
    for (int t = 0; t < 2; ++t)
#pragma unroll
      for (int m = 0; m < 8; ++m)
        pk[t][m] = pack2(p[t][2 * m], p[t][2 * m + 1]);

    __builtin_amdgcn_s_setprio(1);
#pragma unroll
    for (int ks = 0; ks < 4; ++ks) {
      if (ks >= 2 && !act1) break;
      const int t = ks >> 1;
      const int bs = (ks & 1) * 4;
      const u32 s0 = __shfl_xor(pk[t][bs + 0], 32);
      const u32 s1 = __shfl_xor(pk[t][bs + 1], 32);
      const u32 s2 = __shfl_xor(pk[t][bs + 2], 32);
      const u32 s3 = __shfl_xor(pk[t][bs + 3], 32);
      union { u32 u[4]; bf16x8 v; } pa;
      pa.u[0] = hi ? s2 : pk[t][bs + 0];
      pa.u[1] = hi ? s3 : pk[t][bs + 1];
      pa.u[2] = hi ? pk[t][bs + 2] : s0;
      pa.u[3] = hi ? pk[t][bs + 3] : s1;
#pragma unroll
      for (int dt = 0; dt < 4; ++dt) {
        const int d = dt * 32 + l31;
        const bf16x8 vf = *reinterpret_cast<const bf16x8*>(
            &Vt[d * KBLK + (((ks * 2 + hi) ^ ((d >> 2) & 7)) * 8)]);
        oacc[dt] = mfma32(pa.v, vf, oacc[dt]);
      }
    }
    __builtin_amdgcn_s_setprio(0);
  }

  const float li = __builtin_amdgcn_rcpf(lrow);
#pragma unroll
  for (int r = 0; r < 16; ++r) {
    const int rowq = (r & 3) + 8 * (r >> 2) + 4 * hi;
    const float lr = __shfl(li, rowq);
    u16* op = &O[(rowbase + qw + rowq) * DMODEL + hoff + l31];
#pragma unroll
    for (int dt = 0; dt < 4; ++dt) op[dt * 32] = f2bf(oacc[dt][r] * lr);
  }
}

// ---------------- launcher --------------------------------------------
extern "C" void kernel_launch(void* const* d_in, const int* in_sizes, int n_in,
                              void* d_out, int out_size, void* d_ws,
                              size_t ws_size, hipStream_t stream) {
  const int Bv = 2, S = 2048, D = 2048;
  const int M = Bv * S;
  const size_t NT = (size_t)M * D;   // 8388608
  const size_t NW = (size_t)D * D;   // 4194304

  const float* q = (const float*)d_in[0];
  const float* k = (const float*)d_in[1];
  const float* v = (const float*)d_in[2];
  const float* wq_w = (const float*)d_in[4];
  const float* wq_b = (const float*)d_in[5];
  const float* wk_w = (const float*)d_in[6];
  const float* wk_b = (const float*)d_in[7];
  const float* wv_w = (const float*)d_in[8];
  const float* wv_b = (const float*)d_in[9];
  const float* dw = (const float*)d_in[10];
  const float* db = (const float*)d_in[11];
  float* out = (float*)d_out;

  const dim3 blk(256);
  const dim3 gattn(512);
  const size_t need = (7 * NT + 4 * NW) * 2;  // ~151 MB

  if (ws_size >= need) {
    // fused path: all conversions in one launch, Q/K/V GEMMs in one launch
    u16* base = (u16*)d_ws;
    u16* Xq = base;
    u16* Xk = Xq + NT;
    u16* Xv = Xk + NT;
    u16* Wq = Xv + NT;
    u16* Wk = Wq + NW;
    u16* Wv = Wk + NW;
    u16* Wd = Wv + NW;
    u16* Qh = Wd + NW;
    u16* Kh = Qh + NT;
    u16* Vh = Kh + NT;
    u16* Obf = Vh + NT;

    conv_all<<<dim3((unsigned)(NT / 1024), 7), blk, 0, stream>>>(
        q, k, v, wq_w, wk_w, wv_w, dw, Xq, Xk, Xv, Wq, Wk, Wv, Wd, NT, NW);
    gemm_qkv<<<dim3(1536), blk, 0, stream>>>(
        Xq, Xk, Xv, Wq, Wk, Wv, wq_b, wk_b, wv_b, Qh, Kh, Vh);
    flash_attn<<<gattn, blk, 0, stream>>>(Qh, Kh, Vh, Obf);
    gemm_ring<<<dim3(512), blk, 0, stream>>>(Obf, Wd, db, out, 32, D, 1);
  } else {
    // fallback: sequential with buffer reuse (~92 MB)
    u16* Xbf = (u16*)d_ws;
    u16* Wbf = Xbf + NT;
    u16* Qh = Wbf + NW;
    u16* Kh = Qh + NT;
    u16* Vh = Kh + NT;
    u16* Obf = Vh + NT;
    const dim3 gact((unsigned)(NT / 1024));
    const dim3 gw((unsigned)(NW / 1024));

    conv_f32_bf16<<<gact, blk, 0, stream>>>(q, Xbf);
    conv_f32_bf16<<<gw, blk, 0, stream>>>(wq_w, Wbf);
    gemm_ring<<<dim3(512), blk, 0, stream>>>(Xbf, Wbf, wq_b, Qh, 32, D, 0);
    conv_f32_bf16<<<gact, blk, 0, stream>>>(k, Xbf);
    conv_f32_bf16<<<gw, blk, 0, stream>>>(wk_w, Wbf);
    gemm_ring<<<dim3(512), blk, 0, stream>>>(Xbf, Wbf, wk_b, Kh, 32, D, 0);
    conv_f32_bf16<<<gact, blk, 0, stream>>>(v, Xbf);
    conv_f32_bf16<<<gw, blk, 0, stream>>>(wv_w, Wbf);
    gemm_ring<<<dim3(512), blk, 0, stream>>>(Xbf, Wbf, wv_b, Vh, 32, D, 0);
    flash_attn<<<gattn, blk, 0, stream>>>(Qh, Kh, Vh, Obf);
    conv_f32_bf16<<<gw, blk, 0, stream>>>(dw, Wbf);
    gemm_ring<<<dim3(512), blk, 0, stream>>>(Obf, Wbf, db, out, 32, D, 1);
  }
}